// Round 5
// baseline (478.425 us; speedup 1.0000x reference)
//
#include <hip/hip_runtime.h>
#include <hip/hip_bf16.h>
#include <math.h>

#define BB 256
#define TT 64
#define EE 2048
#define DD 512
#define AA 512
#define VV 10000
#define EMBD 256
#define KLSTM (EE + EMBD + DD)   // 2816
#define N4D (4 * DD)             // 2048
#define MROWS (BB * TT)          // 16384 flattened score rows

using bf16x8 = __attribute__((ext_vector_type(8))) __bf16;
using f32x4  = __attribute__((ext_vector_type(4))) float;

__device__ __forceinline__ float sigf(float x) { return 1.f / (1.f + expf(-x)); }

// ---------------- q = hidden @ w1 + b1 + b2 (fold both biases) ----------------
__global__ void k_q(const float* __restrict__ hidden, const float* __restrict__ w1,
                    const float* __restrict__ b1, const float* __restrict__ b2,
                    float* __restrict__ qq) {
    __shared__ float hs[DD];
    const int b = blockIdx.x, tid = threadIdx.x;
    {
        float2 hv = *(const float2*)&hidden[(size_t)b * DD + 2 * tid];
        hs[2 * tid] = hv.x; hs[2 * tid + 1] = hv.y;
    }
    __syncthreads();
    const int a0 = 2 * tid;
    float2 acc = {0.f, 0.f};
    #pragma unroll 4
    for (int k = 0; k < DD; ++k) {
        float2 w = *(const float2*)&w1[(size_t)k * AA + a0];
        float h = hs[k];
        acc.x = fmaf(h, w.x, acc.x);
        acc.y = fmaf(h, w.y, acc.y);
    }
    qq[(size_t)b * AA + a0]     = acc.x + b1[a0]     + b2[a0];
    qq[(size_t)b * AA + a0 + 1] = acc.y + b1[a0 + 1] + b2[a0 + 1];
}

// ---------------- w2t[n][k] = bf16(w2[k][n])  (2048x512 -> 512x2048) ----------------
__global__ void k_w2t(const float* __restrict__ w2, __bf16* __restrict__ w2t) {
    __shared__ float t[32][33];
    const int k0 = blockIdx.x * 32, n0 = blockIdx.y * 32;
    const int tx = threadIdx.x, ty = threadIdx.y;   // block (32,8)
    #pragma unroll
    for (int i = 0; i < 4; ++i)
        t[ty + 8 * i][tx] = w2[(size_t)(k0 + ty + 8 * i) * AA + n0 + tx];
    __syncthreads();
    #pragma unroll
    for (int i = 0; i < 4; ++i)
        w2t[(size_t)(n0 + ty + 8 * i) * EE + k0 + tx] = (__bf16)t[tx][ty + 8 * i];
}

// ------- wxh_t[n][k] = bf16( k<2304 ? wx[k][n] : wh[k-2304][n] ), n<2048, k<2816 -------
__global__ void k_wxht(const float* __restrict__ wx, const float* __restrict__ wh,
                       __bf16* __restrict__ wt) {
    __shared__ float t[32][33];
    const int k0 = blockIdx.x * 32, n0 = blockIdx.y * 32;
    const int tx = threadIdx.x, ty = threadIdx.y;   // block (32,8)
    #pragma unroll
    for (int i = 0; i < 4; ++i) {
        int k = k0 + ty + 8 * i;
        const float* wrow = (k < EE + EMBD) ? &wx[(size_t)k * N4D] : &wh[(size_t)(k - EE - EMBD) * N4D];
        t[ty + 8 * i][tx] = wrow[n0 + tx];
    }
    __syncthreads();
    #pragma unroll
    for (int i = 0; i < 4; ++i)
        wt[(size_t)(n0 + ty + 8 * i) * KLSTM + k0 + tx] = (__bf16)t[tx][ty + 8 * i];
}

// ---- score partial: spart[nb][m] = sum_{n in nb-slice} tanh(q[b(m),n] + enc@w2) * v[n] ----
// GEMM C[16384,512] = enc_flat @ w2 via bf16 MFMA, tiles 128x128, K-step 64.
// grid(4 nb, 128 mb), block 256 = 4 waves (2x2), wave = 64x64 out.
// A (enc f32->bf16) and B (w2t bf16) both staged to XOR-swizzled LDS; next-tile
// global loads issued before the compute barrier (latency hides under MFMA).
__global__ void k_score(const float* __restrict__ enc, const __bf16* __restrict__ w2t,
                        const float* __restrict__ qq, const float* __restrict__ vvec,
                        float* __restrict__ spart) {
    __shared__ bf16x8 Abuf[128][8];      // [row][granule ^ (row&7)]
    __shared__ bf16x8 Bbuf[128][8];
    __shared__ float qsv[2][128], vsv[128], wredL[2][128];
    const int tid = threadIdx.x;
    const int nb = blockIdx.x, mb = blockIdx.y;
    const int n0 = nb * 128, m0 = mb * 128;
    const int b0 = mb * 2;               // rows m0..m0+127 span batches b0, b0+1
    const int l = tid & 63, wv = tid >> 6;
    const int wm = wv >> 1, wn = wv & 1;
    const int ar = l & 15, agr = l >> 4;

    {   // q slice for the two b's, v slice (separate LDS; ordered by loop barriers)
        int i = tid >> 7, col = tid & 127;
        qsv[i][col] = qq[(size_t)(b0 + i) * AA + n0 + col];
        if (tid < 128) vsv[tid] = vvec[n0 + tid];
    }

    // staging geometry
    const int arow = tid >> 1, ahalf = tid & 1;      // A: 2 threads/row, 32 f32 each
    const float* aptr = enc + (size_t)(m0 + arow) * EE + ahalf * 32;
    const int bsub = tid >> 3, bg = tid & 7;         // B: row = i*32+bsub, granule bg
    const int brow7 = bsub & 7;

    f32x4 acc[4][4];
    #pragma unroll
    for (int mi = 0; mi < 4; ++mi)
        #pragma unroll
        for (int ni = 0; ni < 4; ++ni)
            acc[mi][ni] = (f32x4){0.f, 0.f, 0.f, 0.f};

    float4 af[8];
    bf16x8 bstg[4];
    // prologue: tile 0 loads
    #pragma unroll
    for (int j = 0; j < 8; ++j) af[j] = *(const float4*)(aptr + j * 4);
    #pragma unroll
    for (int i = 0; i < 4; ++i)
        bstg[i] = *(const bf16x8*)&w2t[(size_t)(n0 + i * 32 + bsub) * EE + bg * 8];

    const int NIT = EE / 64;   // 32
    for (int it = 0; it < NIT; ++it) {
        if (it > 0) __syncthreads();   // consumers of previous tile done
        // pack + write A (4 granules), write B (4 granules)
        #pragma unroll
        for (int j = 0; j < 4; ++j) {
            bf16x8 pk;
            pk[0] = (__bf16)af[2 * j].x; pk[1] = (__bf16)af[2 * j].y;
            pk[2] = (__bf16)af[2 * j].z; pk[3] = (__bf16)af[2 * j].w;
            pk[4] = (__bf16)af[2 * j + 1].x; pk[5] = (__bf16)af[2 * j + 1].y;
            pk[6] = (__bf16)af[2 * j + 1].z; pk[7] = (__bf16)af[2 * j + 1].w;
            Abuf[arow][(ahalf * 4 + j) ^ (arow & 7)] = pk;
        }
        #pragma unroll
        for (int i = 0; i < 4; ++i)
            Bbuf[i * 32 + bsub][bg ^ brow7] = bstg[i];
        // issue next-tile global loads now; they retire during the compute phase
        if (it + 1 < NIT) {
            const int k1 = (it + 1) * 64;
            #pragma unroll
            for (int j = 0; j < 8; ++j) af[j] = *(const float4*)(aptr + k1 + j * 4);
            #pragma unroll
            for (int i = 0; i < 4; ++i)
                bstg[i] = *(const bf16x8*)&w2t[(size_t)(n0 + i * 32 + bsub) * EE + k1 + bg * 8];
        }
        __syncthreads();               // tile ready
        #pragma unroll
        for (int ks = 0; ks < 2; ++ks) {
            bf16x8 afr[4], bfr[4];
            #pragma unroll
            for (int mi = 0; mi < 4; ++mi)
                afr[mi] = Abuf[wm * 64 + mi * 16 + ar][(ks * 4 + agr) ^ (ar & 7)];
            #pragma unroll
            for (int ni = 0; ni < 4; ++ni)
                bfr[ni] = Bbuf[wn * 64 + ni * 16 + ar][(ks * 4 + agr) ^ (ar & 7)];
            #pragma unroll
            for (int mi = 0; mi < 4; ++mi)
                #pragma unroll
                for (int ni = 0; ni < 4; ++ni)
                    acc[mi][ni] = __builtin_amdgcn_mfma_f32_16x16x32_bf16(afr[mi], bfr[ni], acc[mi][ni], 0, 0, 0);
        }
    }

    // epilogue: tanh(q + s) * v, reduce over this block's 128 n-cols
    float sred[4][4];
    #pragma unroll
    for (int mi = 0; mi < 4; ++mi)
        #pragma unroll
        for (int r = 0; r < 4; ++r) sred[mi][r] = 0.f;
    #pragma unroll
    for (int ni = 0; ni < 4; ++ni) {
        const int col = wn * 64 + ni * 16 + ar;
        const float qa = qsv[wm][col], va = vsv[col];
        #pragma unroll
        for (int mi = 0; mi < 4; ++mi)
            #pragma unroll
            for (int r = 0; r < 4; ++r)
                sred[mi][r] += tanhf(qa + acc[mi][ni][r]) * va;
    }
    #pragma unroll
    for (int mi = 0; mi < 4; ++mi)
        #pragma unroll
        for (int r = 0; r < 4; ++r) {
            #pragma unroll
            for (int off = 1; off < 16; off <<= 1)
                sred[mi][r] += __shfl_xor(sred[mi][r], off, 64);
        }
    if (ar == 0) {
        #pragma unroll
        for (int mi = 0; mi < 4; ++mi)
            #pragma unroll
            for (int r = 0; r < 4; ++r)
                wredL[wn][wm * 64 + mi * 16 + agr * 4 + r] = sred[mi][r];
    }
    __syncthreads();
    if (tid < 128)
        spart[(size_t)nb * MROWS + m0 + tid] = wredL[0][tid] + wredL[1][tid];
}

// ---------------- softmax over t (from 4 partials) + context = sum_t attn * enc ----------------
__global__ void k_context(const float* __restrict__ enc, const float* __restrict__ spart,
                          const float* __restrict__ bv, float* __restrict__ ctx) {
    __shared__ float attn[TT];
    const int b = blockIdx.y;
    const int tid = threadIdx.x;
    if (tid < 64) {
        const int m = b * TT + tid;
        float s = spart[m] + spart[MROWS + m] + spart[2 * MROWS + m] + spart[3 * MROWS + m] + bv[0];
        float mx = s;
        #pragma unroll
        for (int off = 1; off < 64; off <<= 1) mx = fmaxf(mx, __shfl_xor(mx, off, 64));
        float p = expf(s - mx);
        float sum = p;
        #pragma unroll
        for (int off = 1; off < 64; off <<= 1) sum += __shfl_xor(sum, off, 64);
        attn[tid] = p / sum;
    }
    __syncthreads();
    const int e = blockIdx.x * 1024 + tid * 4;
    const float* encb = enc + (size_t)b * TT * EE + e;
    float4 acc = {0.f, 0.f, 0.f, 0.f};
    #pragma unroll 4
    for (int t = 0; t < TT; ++t) {
        float a = attn[t];
        float4 ev = *(const float4*)&encb[(size_t)t * EE];
        acc.x = fmaf(a, ev.x, acc.x);
        acc.y = fmaf(a, ev.y, acc.y);
        acc.z = fmaf(a, ev.z, acc.z);
        acc.w = fmaf(a, ev.w, acc.w);
    }
    *(float4*)&ctx[(size_t)b * EE + e] = acc;
}

// ------- z = [ctx, emb[c], hidden] @ [wx; wh] via bf16 MFMA, K split 4 ways -------
#define ZKS 4
#define ZKC (KLSTM / ZKS)    // 704
#define ZNIT (ZKC / 32)      // 22
__global__ void k_z(const float* __restrict__ ctx, const float* __restrict__ emb,
                    const int* __restrict__ cidx, const float* __restrict__ hidden,
                    const __bf16* __restrict__ wt, float* __restrict__ zp) {
    __shared__ bf16x8 Abuf[32][ZKC / 8];   // [row][granule], granule ^= row&7 (45 KB)
    __shared__ int cbs[32];
    const int tid = threadIdx.x;
    const int l = tid & 63, wv = tid >> 6;
    const int b0  = blockIdx.y * 32;
    const int kc0 = blockIdx.z * ZKC;
    const int nw  = blockIdx.x * 256 + wv * 64;

    if (tid < 32) cbs[tid] = cidx[b0 + tid];
    __syncthreads();

    {
        const int srow = tid >> 3, g0 = tid & 7;
        const int bg = b0 + srow;
        const int erow = cbs[srow];
        #pragma unroll
        for (int i = 0; i < 11; ++i) {
            int g = g0 + 8 * i;
            int k = kc0 + g * 8;
            const float* src;
            if (k < EE)             src = &ctx[(size_t)bg * EE + k];
            else if (k < EE + EMBD) src = &emb[(size_t)erow * EMBD + (k - EE)];
            else                    src = &hidden[(size_t)bg * DD + (k - EE - EMBD)];
            float4 u0 = *(const float4*)src;
            float4 u1 = *(const float4*)(src + 4);
            bf16x8 pk;
            pk[0] = (__bf16)u0.x; pk[1] = (__bf16)u0.y; pk[2] = (__bf16)u0.z; pk[3] = (__bf16)u0.w;
            pk[4] = (__bf16)u1.x; pk[5] = (__bf16)u1.y; pk[6] = (__bf16)u1.z; pk[7] = (__bf16)u1.w;
            Abuf[srow][g ^ (srow & 7)] = pk;
        }
    }
    __syncthreads();

    const int ar = l & 15, agr = l >> 4;
    const __bf16* bbase = wt + (size_t)(nw + ar) * KLSTM + kc0 + agr * 8;

    f32x4 acc[2][4];
    #pragma unroll
    for (int mt = 0; mt < 2; ++mt)
        #pragma unroll
        for (int f = 0; f < 4; ++f)
            acc[mt][f] = (f32x4){0.f, 0.f, 0.f, 0.f};

    bf16x8 bA[4], bBv[4];
    #pragma unroll
    for (int f = 0; f < 4; ++f)
        bA[f] = *(const bf16x8*)(bbase + (size_t)f * 16 * KLSTM);

    for (int itp = 0; itp < ZNIT / 2; ++itp) {
        const int it0 = 2 * itp, it1 = 2 * itp + 1;
        #pragma unroll
        for (int f = 0; f < 4; ++f)
            bBv[f] = *(const bf16x8*)(bbase + (size_t)f * 16 * KLSTM + it1 * 32);
        {
            bf16x8 a0 = Abuf[ar][(it0 * 4 + agr) ^ (ar & 7)];
            bf16x8 a1 = Abuf[16 + ar][(it0 * 4 + agr) ^ (ar & 7)];
            #pragma unroll
            for (int f = 0; f < 4; ++f) {
                acc[0][f] = __builtin_amdgcn_mfma_f32_16x16x32_bf16(a0, bA[f], acc[0][f], 0, 0, 0);
                acc[1][f] = __builtin_amdgcn_mfma_f32_16x16x32_bf16(a1, bA[f], acc[1][f], 0, 0, 0);
            }
        }
        const int it2 = (it1 + 1 < ZNIT) ? it1 + 1 : it1;
        #pragma unroll
        for (int f = 0; f < 4; ++f)
            bA[f] = *(const bf16x8*)(bbase + (size_t)f * 16 * KLSTM + it2 * 32);
        {
            bf16x8 a0 = Abuf[ar][(it1 * 4 + agr) ^ (ar & 7)];
            bf16x8 a1 = Abuf[16 + ar][(it1 * 4 + agr) ^ (ar & 7)];
            #pragma unroll
            for (int f = 0; f < 4; ++f) {
                acc[0][f] = __builtin_amdgcn_mfma_f32_16x16x32_bf16(a0, bBv[f], acc[0][f], 0, 0, 0);
                acc[1][f] = __builtin_amdgcn_mfma_f32_16x16x32_bf16(a1, bBv[f], acc[1][f], 0, 0, 0);
            }
        }
    }

    float* zpo = zp + (size_t)blockIdx.z * BB * N4D;
    #pragma unroll
    for (int mt = 0; mt < 2; ++mt)
        #pragma unroll
        for (int f = 0; f < 4; ++f)
            #pragma unroll
            for (int r = 0; r < 4; ++r)
                zpo[(size_t)(b0 + mt * 16 + agr * 4 + r) * N4D + nw + f * 16 + ar] = acc[mt][f][r];
}

// ---------------- LSTM gates: sum K-split partials + bias, then activations ----------------
__global__ void k_gates(const float* __restrict__ zp, const float* __restrict__ carry,
                        const float* __restrict__ bl,
                        float* __restrict__ hout, float* __restrict__ cout) {
    const int b = blockIdx.x, tid = threadIdx.x;
    const size_t P = (size_t)BB * N4D;
    #pragma unroll
    for (int r = 0; r < 2; ++r) {
        int d = tid + r * 256;
        float zi = bl[d], zf = bl[DD + d], zg = bl[2 * DD + d], zo = bl[3 * DD + d];
        #pragma unroll
        for (int ks = 0; ks < ZKS; ++ks) {
            const float* zb = zp + ks * P + (size_t)b * N4D;
            zi += zb[d];
            zf += zb[DD + d];
            zg += zb[2 * DD + d];
            zo += zb[3 * DD + d];
        }
        float c = carry[(size_t)b * DD + d];
        float cn = sigf(zf) * c + sigf(zi) * tanhf(zg);
        float hn = sigf(zo) * tanhf(cn);
        cout[(size_t)b * DD + d] = cn;
        hout[(size_t)b * DD + d] = hn;
    }
}

// ---------------- logits = h_new @ wp + bp ----------------
__global__ void k_logits(const float* __restrict__ hnew, const float* __restrict__ wp,
                         const float* __restrict__ bp, float* __restrict__ logits) {
    __shared__ float hs[32][64];
    const int j0 = blockIdx.x * 64;
    const int b0 = blockIdx.y * 32;
    const int tid = threadIdx.x;
    const int tx = tid & 63, ty = tid >> 6;
    const int j = j0 + tx;
    const int jc = (j < VV) ? j : (VV - 1);

    float acc[8];
    #pragma unroll
    for (int r = 0; r < 8; ++r) acc[r] = 0.f;

    for (int k0 = 0; k0 < DD; k0 += 64) {
        __syncthreads();
        #pragma unroll
        for (int r = 0; r < 8; ++r) {
            int flat = r * 256 + tid;
            int bb = flat >> 6;
            int kk = flat & 63;
            hs[bb][kk] = hnew[(size_t)(b0 + bb) * DD + k0 + kk];
        }
        __syncthreads();
        for (int kk = 0; kk < 64; kk += 4) {
            int kg = k0 + kk;
            float w0  = wp[(size_t)kg * VV + jc];
            float w1v = wp[(size_t)(kg + 1) * VV + jc];
            float w2v = wp[(size_t)(kg + 2) * VV + jc];
            float w3v = wp[(size_t)(kg + 3) * VV + jc];
            #pragma unroll
            for (int r = 0; r < 8; ++r) {
                int bb = ty + 4 * r;
                float4 hv = *(const float4*)&hs[bb][kk];
                acc[r] = fmaf(hv.x, w0, acc[r]);
                acc[r] = fmaf(hv.y, w1v, acc[r]);
                acc[r] = fmaf(hv.z, w2v, acc[r]);
                acc[r] = fmaf(hv.w, w3v, acc[r]);
            }
        }
    }
    if (j < VV) {
        const float bpj = bp[j];
        #pragma unroll
        for (int r = 0; r < 8; ++r) {
            int bg = b0 + ty + 4 * r;
            logits[(size_t)bg * VV + j] = acc[r] + bpj;
        }
    }
}

extern "C" void kernel_launch(void* const* d_in, const int* in_sizes, int n_in,
                              void* d_out, int out_size, void* d_ws, size_t ws_size,
                              hipStream_t stream) {
    const int*   cidx   = (const int*)d_in[0];
    const float* hidden = (const float*)d_in[1];
    const float* carry  = (const float*)d_in[2];
    const float* enc    = (const float*)d_in[3];
    const float* emb    = (const float*)d_in[4];
    const float* w1     = (const float*)d_in[5];
    const float* b1     = (const float*)d_in[6];
    const float* w2     = (const float*)d_in[7];
    const float* b2     = (const float*)d_in[8];
    const float* vvec   = (const float*)d_in[9];
    const float* bv     = (const float*)d_in[10];
    const float* wx     = (const float*)d_in[11];
    const float* wh     = (const float*)d_in[12];
    const float* bl     = (const float*)d_in[13];
    const float* wp     = (const float*)d_in[14];
    const float* bp     = (const float*)d_in[15];

    float* out    = (float*)d_out;
    float* logits = out;
    float* hout   = out + (size_t)BB * VV;
    float* cout   = hout + (size_t)BB * DD;

    float* ws    = (float*)d_ws;
    float* qq    = ws;                          // B*A            = 131072 f32
    float* score = qq + (size_t)BB * AA;        // (unused now, keep layout)
    float* ctx   = score + (size_t)BB * TT;     // B*E            = 524288 f32
    float* zp    = ctx + (size_t)BB * EE;       // ZKS*B*4D       = 2097152 f32
    __bf16* wxh_t = (__bf16*)(zp + (size_t)ZKS * BB * N4D);   // 2048*2816 bf16 = 11.5 MB
    float* spart = (float*)(wxh_t + (size_t)N4D * KLSTM);     // 4*16384 f32 = 256 KB
    // w2t (512x2048 bf16 = 2 MB) aliases ctx: consumed by k_score BEFORE k_context writes ctx
    __bf16* w2t  = (__bf16*)ctx;

    hipLaunchKernelGGL(k_w2t,     dim3(EE / 32, AA / 32),    dim3(32, 8), 0, stream, w2, w2t);
    hipLaunchKernelGGL(k_wxht,    dim3(KLSTM / 32, N4D / 32), dim3(32, 8), 0, stream, wx, wh, wxh_t);
    hipLaunchKernelGGL(k_q,       dim3(BB),                  dim3(256), 0, stream, hidden, w1, b1, b2, qq);
    hipLaunchKernelGGL(k_score,   dim3(4, MROWS / 128),      dim3(256), 0, stream, enc, w2t, qq, vvec, spart);
    hipLaunchKernelGGL(k_context, dim3(2, BB),               dim3(256), 0, stream, enc, spart, bv, ctx);
    hipLaunchKernelGGL(k_z,       dim3(N4D / 256, BB / 32, ZKS), dim3(256), 0, stream, ctx, emb, cidx, hidden, wxh_t, zp);
    hipLaunchKernelGGL(k_gates,   dim3(BB),                  dim3(256), 0, stream, zp, carry, bl, hout, cout);
    hipLaunchKernelGGL(k_logits,  dim3((VV + 63) / 64, BB / 32), dim3(256), 0, stream, hout, wp, bp, logits);
}

// Round 6
// 277.525 us; speedup vs baseline: 1.7239x; 1.7239x over previous
//
#include <hip/hip_runtime.h>
#include <hip/hip_bf16.h>
#include <math.h>

#define BB 256
#define TT 64
#define EE 2048
#define DD 512
#define AA 512
#define VV 10000
#define EMBD 256
#define KLSTM (EE + EMBD + DD)   // 2816
#define N4D (4 * DD)             // 2048
#define MROWS (BB * TT)          // 16384 flattened score rows

using bf16x8 = __attribute__((ext_vector_type(8))) __bf16;
using f32x4  = __attribute__((ext_vector_type(4))) float;

__device__ __forceinline__ float sigf(float x) { return 1.f / (1.f + expf(-x)); }

// ---------------- q = hidden @ w1 + b1 + b2 (fold both biases) ----------------
__global__ void k_q(const float* __restrict__ hidden, const float* __restrict__ w1,
                    const float* __restrict__ b1, const float* __restrict__ b2,
                    float* __restrict__ qq) {
    __shared__ float hs[DD];
    const int b = blockIdx.x, tid = threadIdx.x;
    {
        float2 hv = *(const float2*)&hidden[(size_t)b * DD + 2 * tid];
        hs[2 * tid] = hv.x; hs[2 * tid + 1] = hv.y;
    }
    __syncthreads();
    const int a0 = 2 * tid;
    float2 acc = {0.f, 0.f};
    #pragma unroll 4
    for (int k = 0; k < DD; ++k) {
        float2 w = *(const float2*)&w1[(size_t)k * AA + a0];
        float h = hs[k];
        acc.x = fmaf(h, w.x, acc.x);
        acc.y = fmaf(h, w.y, acc.y);
    }
    qq[(size_t)b * AA + a0]     = acc.x + b1[a0]     + b2[a0];
    qq[(size_t)b * AA + a0 + 1] = acc.y + b1[a0 + 1] + b2[a0 + 1];
}

// ---------------- w2t[n][k] = bf16(w2[k][n])  (2048x512 -> 512x2048) ----------------
__global__ void k_w2t(const float* __restrict__ w2, __bf16* __restrict__ w2t) {
    __shared__ float t[32][33];
    const int k0 = blockIdx.x * 32, n0 = blockIdx.y * 32;
    const int tx = threadIdx.x, ty = threadIdx.y;   // block (32,8)
    #pragma unroll
    for (int i = 0; i < 4; ++i)
        t[ty + 8 * i][tx] = w2[(size_t)(k0 + ty + 8 * i) * AA + n0 + tx];
    __syncthreads();
    #pragma unroll
    for (int i = 0; i < 4; ++i)
        w2t[(size_t)(n0 + ty + 8 * i) * EE + k0 + tx] = (__bf16)t[tx][ty + 8 * i];
}

// ------- wxh_t[n][k] = bf16( k<2304 ? wx[k][n] : wh[k-2304][n] ), n<2048, k<2816 -------
__global__ void k_wxht(const float* __restrict__ wx, const float* __restrict__ wh,
                       __bf16* __restrict__ wt) {
    __shared__ float t[32][33];
    const int k0 = blockIdx.x * 32, n0 = blockIdx.y * 32;
    const int tx = threadIdx.x, ty = threadIdx.y;   // block (32,8)
    #pragma unroll
    for (int i = 0; i < 4; ++i) {
        int k = k0 + ty + 8 * i;
        const float* wrow = (k < EE + EMBD) ? &wx[(size_t)k * N4D] : &wh[(size_t)(k - EE - EMBD) * N4D];
        t[ty + 8 * i][tx] = wrow[n0 + tx];
    }
    __syncthreads();
    #pragma unroll
    for (int i = 0; i < 4; ++i)
        wt[(size_t)(n0 + ty + 8 * i) * KLSTM + k0 + tx] = (__bf16)t[tx][ty + 8 * i];
}

// ---- score partial: spart[nb][m] = sum_{n in nb-slice} tanh(q[b(m),n] + enc@w2) * v[n] ----
// GEMM C[16384,512] = enc_flat @ w2 via bf16 MFMA. Tile M=64 (one batch), N=128, K-step 64.
// grid = flat 1024: mb = id&255 (fast), nb = id>>8 -> the 4 nb-blocks of an mb land on
// the SAME CU (slots c, c+256, c+512, c+768) => enc fetched from HBM once, L1/L2-shared.
// 4 blocks/CU for latency hiding. Both operands LDS-staged, XOR-swizzled, issue-early.
__global__ __launch_bounds__(256, 4) void k_score(
        const float* __restrict__ enc, const __bf16* __restrict__ w2t,
        const float* __restrict__ qq, const float* __restrict__ vvec,
        float* __restrict__ spart) {
    __shared__ bf16x8 Abuf[64][8];       // [row][granule ^ (row&7)]  8 KB
    __shared__ bf16x8 Bbuf[128][8];      // 16 KB
    __shared__ float qsv[128], vsv[128], wredL[2][64];
    const int tid = threadIdx.x;
    const int mb = blockIdx.x & 255, nb = blockIdx.x >> 8;
    const int m0 = mb * 64, n0 = nb * 128;
    const int l = tid & 63, wv = tid >> 6;
    const int wm = wv >> 1, wn = wv & 1;           // 2x2 waves, wave tile 32m x 64n
    const int ar = l & 15, agr = l >> 4;

    if (tid < 128) qsv[tid] = qq[(size_t)mb * AA + n0 + tid];
    else           vsv[tid - 128] = vvec[n0 + tid - 128];

    // staging geometry: A = 64 rows x 64 k (4 threads/row, 16 f32 each)
    const int arow = tid >> 2, ag0 = (tid & 3) * 2;
    const float* aptr = enc + (size_t)(m0 + arow) * EE + ag0 * 8;
    // B = 128 n-rows x 64 k (2 threads/row, 32 bf16 each)
    const int brow = tid >> 1, bg0 = (tid & 1) * 4;
    const __bf16* bptr = w2t + (size_t)(n0 + brow) * EE + bg0 * 8;

    f32x4 acc[2][4];
    #pragma unroll
    for (int mi = 0; mi < 2; ++mi)
        #pragma unroll
        for (int ni = 0; ni < 4; ++ni)
            acc[mi][ni] = (f32x4){0.f, 0.f, 0.f, 0.f};

    float4 af[4];
    bf16x8 bstg[4];
    #pragma unroll
    for (int j = 0; j < 4; ++j) af[j] = *(const float4*)(aptr + j * 4);
    #pragma unroll
    for (int i = 0; i < 4; ++i) bstg[i] = *(const bf16x8*)(bptr + i * 8);

    const int NIT = EE / 64;   // 32
    for (int it = 0; it < NIT; ++it) {
        if (it > 0) __syncthreads();   // previous tile consumed
        {   // pack + write A (2 granules), B (4 granules)
            bf16x8 pk;
            pk[0] = (__bf16)af[0].x; pk[1] = (__bf16)af[0].y; pk[2] = (__bf16)af[0].z; pk[3] = (__bf16)af[0].w;
            pk[4] = (__bf16)af[1].x; pk[5] = (__bf16)af[1].y; pk[6] = (__bf16)af[1].z; pk[7] = (__bf16)af[1].w;
            Abuf[arow][ag0 ^ (arow & 7)] = pk;
            pk[0] = (__bf16)af[2].x; pk[1] = (__bf16)af[2].y; pk[2] = (__bf16)af[2].z; pk[3] = (__bf16)af[2].w;
            pk[4] = (__bf16)af[3].x; pk[5] = (__bf16)af[3].y; pk[6] = (__bf16)af[3].z; pk[7] = (__bf16)af[3].w;
            Abuf[arow][(ag0 + 1) ^ (arow & 7)] = pk;
        }
        #pragma unroll
        for (int i = 0; i < 4; ++i)
            Bbuf[brow][(bg0 + i) ^ (brow & 7)] = bstg[i];
        if (it + 1 < NIT) {            // issue next tile now; retires under MFMA
            const int k1 = (it + 1) * 64;
            #pragma unroll
            for (int j = 0; j < 4; ++j) af[j] = *(const float4*)(aptr + k1 + j * 4);
            #pragma unroll
            for (int i = 0; i < 4; ++i) bstg[i] = *(const bf16x8*)(bptr + k1 + i * 8);
        }
        __syncthreads();               // tile ready
        #pragma unroll
        for (int ks = 0; ks < 2; ++ks) {
            bf16x8 afr[2], bfr[4];
            #pragma unroll
            for (int mi = 0; mi < 2; ++mi)
                afr[mi] = Abuf[wm * 32 + mi * 16 + ar][(ks * 4 + agr) ^ (ar & 7)];
            #pragma unroll
            for (int ni = 0; ni < 4; ++ni)
                bfr[ni] = Bbuf[wn * 64 + ni * 16 + ar][(ks * 4 + agr) ^ (ar & 7)];
            #pragma unroll
            for (int mi = 0; mi < 2; ++mi)
                #pragma unroll
                for (int ni = 0; ni < 4; ++ni)
                    acc[mi][ni] = __builtin_amdgcn_mfma_f32_16x16x32_bf16(afr[mi], bfr[ni], acc[mi][ni], 0, 0, 0);
        }
    }

    // epilogue: tanh(q + s) * v, reduce over this block's 128 n-cols
    float sred[2][4];
    #pragma unroll
    for (int mi = 0; mi < 2; ++mi)
        #pragma unroll
        for (int r = 0; r < 4; ++r) sred[mi][r] = 0.f;
    #pragma unroll
    for (int ni = 0; ni < 4; ++ni) {
        const int col = wn * 64 + ni * 16 + ar;
        const float qa = qsv[col], va = vsv[col];
        #pragma unroll
        for (int mi = 0; mi < 2; ++mi)
            #pragma unroll
            for (int r = 0; r < 4; ++r)
                sred[mi][r] += tanhf(qa + acc[mi][ni][r]) * va;
    }
    #pragma unroll
    for (int mi = 0; mi < 2; ++mi)
        #pragma unroll
        for (int r = 0; r < 4; ++r) {
            #pragma unroll
            for (int off = 1; off < 16; off <<= 1)
                sred[mi][r] += __shfl_xor(sred[mi][r], off, 64);
        }
    if (ar == 0) {
        #pragma unroll
        for (int mi = 0; mi < 2; ++mi)
            #pragma unroll
            for (int r = 0; r < 4; ++r)
                wredL[wn][wm * 32 + mi * 16 + agr * 4 + r] = sred[mi][r];
    }
    __syncthreads();
    if (tid < 64)
        spart[(size_t)nb * MROWS + m0 + tid] = wredL[0][tid] + wredL[1][tid];
}

// ---------------- softmax over t (from 4 partials) + context = sum_t attn * enc ----------------
__global__ void k_context(const float* __restrict__ enc, const float* __restrict__ spart,
                          const float* __restrict__ bv, float* __restrict__ ctx) {
    __shared__ float attn[TT];
    const int b = blockIdx.y;
    const int tid = threadIdx.x;
    if (tid < 64) {
        const int m = b * TT + tid;
        float s = spart[m] + spart[MROWS + m] + spart[2 * MROWS + m] + spart[3 * MROWS + m] + bv[0];
        float mx = s;
        #pragma unroll
        for (int off = 1; off < 64; off <<= 1) mx = fmaxf(mx, __shfl_xor(mx, off, 64));
        float p = expf(s - mx);
        float sum = p;
        #pragma unroll
        for (int off = 1; off < 64; off <<= 1) sum += __shfl_xor(sum, off, 64);
        attn[tid] = p / sum;
    }
    __syncthreads();
    const int e = blockIdx.x * 1024 + tid * 4;
    const float* encb = enc + (size_t)b * TT * EE + e;
    float4 acc = {0.f, 0.f, 0.f, 0.f};
    #pragma unroll 4
    for (int t = 0; t < TT; ++t) {
        float a = attn[t];
        float4 ev = *(const float4*)&encb[(size_t)t * EE];
        acc.x = fmaf(a, ev.x, acc.x);
        acc.y = fmaf(a, ev.y, acc.y);
        acc.z = fmaf(a, ev.z, acc.z);
        acc.w = fmaf(a, ev.w, acc.w);
    }
    *(float4*)&ctx[(size_t)b * EE + e] = acc;
}

// ------- z = [ctx, emb[c], hidden] @ [wx; wh] via bf16 MFMA, K split 4 ways -------
#define ZKS 4
#define ZKC (KLSTM / ZKS)    // 704
#define ZNIT (ZKC / 32)      // 22
__global__ void k_z(const float* __restrict__ ctx, const float* __restrict__ emb,
                    const int* __restrict__ cidx, const float* __restrict__ hidden,
                    const __bf16* __restrict__ wt, float* __restrict__ zp) {
    __shared__ bf16x8 Abuf[32][ZKC / 8];   // [row][granule], granule ^= row&7 (45 KB)
    __shared__ int cbs[32];
    const int tid = threadIdx.x;
    const int l = tid & 63, wv = tid >> 6;
    const int b0  = blockIdx.y * 32;
    const int kc0 = blockIdx.z * ZKC;
    const int nw  = blockIdx.x * 256 + wv * 64;

    if (tid < 32) cbs[tid] = cidx[b0 + tid];
    __syncthreads();

    {
        const int srow = tid >> 3, g0 = tid & 7;
        const int bg = b0 + srow;
        const int erow = cbs[srow];
        #pragma unroll
        for (int i = 0; i < 11; ++i) {
            int g = g0 + 8 * i;
            int k = kc0 + g * 8;
            const float* src;
            if (k < EE)             src = &ctx[(size_t)bg * EE + k];
            else if (k < EE + EMBD) src = &emb[(size_t)erow * EMBD + (k - EE)];
            else                    src = &hidden[(size_t)bg * DD + (k - EE - EMBD)];
            float4 u0 = *(const float4*)src;
            float4 u1 = *(const float4*)(src + 4);
            bf16x8 pk;
            pk[0] = (__bf16)u0.x; pk[1] = (__bf16)u0.y; pk[2] = (__bf16)u0.z; pk[3] = (__bf16)u0.w;
            pk[4] = (__bf16)u1.x; pk[5] = (__bf16)u1.y; pk[6] = (__bf16)u1.z; pk[7] = (__bf16)u1.w;
            Abuf[srow][g ^ (srow & 7)] = pk;
        }
    }
    __syncthreads();

    const int ar = l & 15, agr = l >> 4;
    const __bf16* bbase = wt + (size_t)(nw + ar) * KLSTM + kc0 + agr * 8;

    f32x4 acc[2][4];
    #pragma unroll
    for (int mt = 0; mt < 2; ++mt)
        #pragma unroll
        for (int f = 0; f < 4; ++f)
            acc[mt][f] = (f32x4){0.f, 0.f, 0.f, 0.f};

    bf16x8 bA[4], bBv[4];
    #pragma unroll
    for (int f = 0; f < 4; ++f)
        bA[f] = *(const bf16x8*)(bbase + (size_t)f * 16 * KLSTM);

    for (int itp = 0; itp < ZNIT / 2; ++itp) {
        const int it0 = 2 * itp, it1 = 2 * itp + 1;
        #pragma unroll
        for (int f = 0; f < 4; ++f)
            bBv[f] = *(const bf16x8*)(bbase + (size_t)f * 16 * KLSTM + it1 * 32);
        {
            bf16x8 a0 = Abuf[ar][(it0 * 4 + agr) ^ (ar & 7)];
            bf16x8 a1 = Abuf[16 + ar][(it0 * 4 + agr) ^ (ar & 7)];
            #pragma unroll
            for (int f = 0; f < 4; ++f) {
                acc[0][f] = __builtin_amdgcn_mfma_f32_16x16x32_bf16(a0, bA[f], acc[0][f], 0, 0, 0);
                acc[1][f] = __builtin_amdgcn_mfma_f32_16x16x32_bf16(a1, bA[f], acc[1][f], 0, 0, 0);
            }
        }
        const int it2 = (it1 + 1 < ZNIT) ? it1 + 1 : it1;
        #pragma unroll
        for (int f = 0; f < 4; ++f)
            bA[f] = *(const bf16x8*)(bbase + (size_t)f * 16 * KLSTM + it2 * 32);
        {
            bf16x8 a0 = Abuf[ar][(it1 * 4 + agr) ^ (ar & 7)];
            bf16x8 a1 = Abuf[16 + ar][(it1 * 4 + agr) ^ (ar & 7)];
            #pragma unroll
            for (int f = 0; f < 4; ++f) {
                acc[0][f] = __builtin_amdgcn_mfma_f32_16x16x32_bf16(a0, bBv[f], acc[0][f], 0, 0, 0);
                acc[1][f] = __builtin_amdgcn_mfma_f32_16x16x32_bf16(a1, bBv[f], acc[1][f], 0, 0, 0);
            }
        }
    }

    float* zpo = zp + (size_t)blockIdx.z * BB * N4D;
    #pragma unroll
    for (int mt = 0; mt < 2; ++mt)
        #pragma unroll
        for (int f = 0; f < 4; ++f)
            #pragma unroll
            for (int r = 0; r < 4; ++r)
                zpo[(size_t)(b0 + mt * 16 + agr * 4 + r) * N4D + nw + f * 16 + ar] = acc[mt][f][r];
}

// ---------------- LSTM gates: sum K-split partials + bias, then activations ----------------
__global__ void k_gates(const float* __restrict__ zp, const float* __restrict__ carry,
                        const float* __restrict__ bl,
                        float* __restrict__ hout, float* __restrict__ cout) {
    const int b = blockIdx.x, tid = threadIdx.x;
    const size_t P = (size_t)BB * N4D;
    #pragma unroll
    for (int r = 0; r < 2; ++r) {
        int d = tid + r * 256;
        float zi = bl[d], zf = bl[DD + d], zg = bl[2 * DD + d], zo = bl[3 * DD + d];
        #pragma unroll
        for (int ks = 0; ks < ZKS; ++ks) {
            const float* zb = zp + ks * P + (size_t)b * N4D;
            zi += zb[d];
            zf += zb[DD + d];
            zg += zb[2 * DD + d];
            zo += zb[3 * DD + d];
        }
        float c = carry[(size_t)b * DD + d];
        float cn = sigf(zf) * c + sigf(zi) * tanhf(zg);
        float hn = sigf(zo) * tanhf(cn);
        cout[(size_t)b * DD + d] = cn;
        hout[(size_t)b * DD + d] = hn;
    }
}

// ---------------- logits = h_new @ wp + bp ----------------
__global__ void k_logits(const float* __restrict__ hnew, const float* __restrict__ wp,
                         const float* __restrict__ bp, float* __restrict__ logits) {
    __shared__ float hs[32][64];
    const int j0 = blockIdx.x * 64;
    const int b0 = blockIdx.y * 32;
    const int tid = threadIdx.x;
    const int tx = tid & 63, ty = tid >> 6;
    const int j = j0 + tx;
    const int jc = (j < VV) ? j : (VV - 1);

    float acc[8];
    #pragma unroll
    for (int r = 0; r < 8; ++r) acc[r] = 0.f;

    for (int k0 = 0; k0 < DD; k0 += 64) {
        __syncthreads();
        #pragma unroll
        for (int r = 0; r < 8; ++r) {
            int flat = r * 256 + tid;
            int bb = flat >> 6;
            int kk = flat & 63;
            hs[bb][kk] = hnew[(size_t)(b0 + bb) * DD + k0 + kk];
        }
        __syncthreads();
        for (int kk = 0; kk < 64; kk += 4) {
            int kg = k0 + kk;
            float w0  = wp[(size_t)kg * VV + jc];
            float w1v = wp[(size_t)(kg + 1) * VV + jc];
            float w2v = wp[(size_t)(kg + 2) * VV + jc];
            float w3v = wp[(size_t)(kg + 3) * VV + jc];
            #pragma unroll
            for (int r = 0; r < 8; ++r) {
                int bb = ty + 4 * r;
                float4 hv = *(const float4*)&hs[bb][kk];
                acc[r] = fmaf(hv.x, w0, acc[r]);
                acc[r] = fmaf(hv.y, w1v, acc[r]);
                acc[r] = fmaf(hv.z, w2v, acc[r]);
                acc[r] = fmaf(hv.w, w3v, acc[r]);
            }
        }
    }
    if (j < VV) {
        const float bpj = bp[j];
        #pragma unroll
        for (int r = 0; r < 8; ++r) {
            int bg = b0 + ty + 4 * r;
            logits[(size_t)bg * VV + j] = acc[r] + bpj;
        }
    }
}

extern "C" void kernel_launch(void* const* d_in, const int* in_sizes, int n_in,
                              void* d_out, int out_size, void* d_ws, size_t ws_size,
                              hipStream_t stream) {
    const int*   cidx   = (const int*)d_in[0];
    const float* hidden = (const float*)d_in[1];
    const float* carry  = (const float*)d_in[2];
    const float* enc    = (const float*)d_in[3];
    const float* emb    = (const float*)d_in[4];
    const float* w1     = (const float*)d_in[5];
    const float* b1     = (const float*)d_in[6];
    const float* w2     = (const float*)d_in[7];
    const float* b2     = (const float*)d_in[8];
    const float* vvec   = (const float*)d_in[9];
    const float* bv     = (const float*)d_in[10];
    const float* wx     = (const float*)d_in[11];
    const float* wh     = (const float*)d_in[12];
    const float* bl     = (const float*)d_in[13];
    const float* wp     = (const float*)d_in[14];
    const float* bp     = (const float*)d_in[15];

    float* out    = (float*)d_out;
    float* logits = out;
    float* hout   = out + (size_t)BB * VV;
    float* cout   = hout + (size_t)BB * DD;

    float* ws    = (float*)d_ws;
    float* qq    = ws;                          // B*A            = 131072 f32
    float* score = qq + (size_t)BB * AA;        // (layout keep)
    float* ctx   = score + (size_t)BB * TT;     // B*E            = 524288 f32
    float* zp    = ctx + (size_t)BB * EE;       // ZKS*B*4D       = 2097152 f32
    __bf16* wxh_t = (__bf16*)(zp + (size_t)ZKS * BB * N4D);   // 2048*2816 bf16 = 11.5 MB
    float* spart = (float*)(wxh_t + (size_t)N4D * KLSTM);     // 4*16384 f32 = 256 KB
    // w2t (512x2048 bf16 = 2 MB) aliases ctx: consumed by k_score BEFORE k_context writes ctx
    __bf16* w2t  = (__bf16*)ctx;

    hipLaunchKernelGGL(k_w2t,     dim3(EE / 32, AA / 32),    dim3(32, 8), 0, stream, w2, w2t);
    hipLaunchKernelGGL(k_wxht,    dim3(KLSTM / 32, N4D / 32), dim3(32, 8), 0, stream, wx, wh, wxh_t);
    hipLaunchKernelGGL(k_q,       dim3(BB),                  dim3(256), 0, stream, hidden, w1, b1, b2, qq);
    hipLaunchKernelGGL(k_score,   dim3(1024),                dim3(256), 0, stream, enc, w2t, qq, vvec, spart);
    hipLaunchKernelGGL(k_context, dim3(2, BB),               dim3(256), 0, stream, enc, spart, bv, ctx);
    hipLaunchKernelGGL(k_z,       dim3(N4D / 256, BB / 32, ZKS), dim3(256), 0, stream, ctx, emb, cidx, hidden, wxh_t, zp);
    hipLaunchKernelGGL(k_gates,   dim3(BB),                  dim3(256), 0, stream, zp, carry, bl, hout, cout);
    hipLaunchKernelGGL(k_logits,  dim3((VV + 63) / 64, BB / 32), dim3(256), 0, stream, hout, wp, bp, logits);
}

// Round 7
// 208.126 us; speedup vs baseline: 2.2987x; 1.3334x over previous
//
#include <hip/hip_runtime.h>
#include <hip/hip_bf16.h>
#include <math.h>

#define BB 256
#define TT 64
#define EE 2048
#define DD 512
#define AA 512
#define VV 10000
#define VPAD 10240               // 80 * 128
#define EMBD 256
#define KLSTM (EE + EMBD + DD)   // 2816
#define N4D (4 * DD)             // 2048
#define MROWS (BB * TT)          // 16384 flattened score rows

using bf16x8 = __attribute__((ext_vector_type(8))) __bf16;
using f32x4  = __attribute__((ext_vector_type(4))) float;

__device__ __forceinline__ float sigf(float x) { return 1.f / (1.f + expf(-x)); }

// ---------------- q = hidden @ w1 + b1 + b2 (fold both biases) ----------------
__global__ void k_q(const float* __restrict__ hidden, const float* __restrict__ w1,
                    const float* __restrict__ b1, const float* __restrict__ b2,
                    float* __restrict__ qq) {
    __shared__ float hs[DD];
    const int b = blockIdx.x, tid = threadIdx.x;
    {
        float2 hv = *(const float2*)&hidden[(size_t)b * DD + 2 * tid];
        hs[2 * tid] = hv.x; hs[2 * tid + 1] = hv.y;
    }
    __syncthreads();
    const int a0 = 2 * tid;
    float2 acc = {0.f, 0.f};
    #pragma unroll 4
    for (int k = 0; k < DD; ++k) {
        float2 w = *(const float2*)&w1[(size_t)k * AA + a0];
        float h = hs[k];
        acc.x = fmaf(h, w.x, acc.x);
        acc.y = fmaf(h, w.y, acc.y);
    }
    qq[(size_t)b * AA + a0]     = acc.x + b1[a0]     + b2[a0];
    qq[(size_t)b * AA + a0 + 1] = acc.y + b1[a0 + 1] + b2[a0 + 1];
}

// ---------------- w2t[n][k] = bf16(w2[k][n])  (2048x512 -> 512x2048) ----------------
__global__ void k_w2t(const float* __restrict__ w2, __bf16* __restrict__ w2t) {
    __shared__ float t[32][33];
    const int k0 = blockIdx.x * 32, n0 = blockIdx.y * 32;
    const int tx = threadIdx.x, ty = threadIdx.y;   // block (32,8)
    #pragma unroll
    for (int i = 0; i < 4; ++i)
        t[ty + 8 * i][tx] = w2[(size_t)(k0 + ty + 8 * i) * AA + n0 + tx];
    __syncthreads();
    #pragma unroll
    for (int i = 0; i < 4; ++i)
        w2t[(size_t)(n0 + ty + 8 * i) * EE + k0 + tx] = (__bf16)t[tx][ty + 8 * i];
}

// ------- wxh_t[n][k] = bf16( k<2304 ? wx[k][n] : wh[k-2304][n] ), n<2048, k<2816 -------
__global__ void k_wxht(const float* __restrict__ wx, const float* __restrict__ wh,
                       __bf16* __restrict__ wt) {
    __shared__ float t[32][33];
    const int k0 = blockIdx.x * 32, n0 = blockIdx.y * 32;
    const int tx = threadIdx.x, ty = threadIdx.y;   // block (32,8)
    #pragma unroll
    for (int i = 0; i < 4; ++i) {
        int k = k0 + ty + 8 * i;
        const float* wrow = (k < EE + EMBD) ? &wx[(size_t)k * N4D] : &wh[(size_t)(k - EE - EMBD) * N4D];
        t[ty + 8 * i][tx] = wrow[n0 + tx];
    }
    __syncthreads();
    #pragma unroll
    for (int i = 0; i < 4; ++i)
        wt[(size_t)(n0 + ty + 8 * i) * KLSTM + k0 + tx] = (__bf16)t[tx][ty + 8 * i];
}

// ------- wpt[n][k] = bf16(wp[k][n]), n < VPAD (tail rows clamp-read, masked at use) -------
__global__ void k_wpt(const float* __restrict__ wp, __bf16* __restrict__ wpt) {
    __shared__ float t[32][33];
    const int k0 = blockIdx.x * 32, n0 = blockIdx.y * 32;
    const int tx = threadIdx.x, ty = threadIdx.y;   // block (32,8)
    #pragma unroll
    for (int i = 0; i < 4; ++i) {
        int n = n0 + tx;
        t[ty + 8 * i][tx] = wp[(size_t)(k0 + ty + 8 * i) * VV + (n < VV ? n : VV - 1)];
    }
    __syncthreads();
    #pragma unroll
    for (int i = 0; i < 4; ++i)
        wpt[(size_t)(n0 + ty + 8 * i) * DD + k0 + tx] = (__bf16)t[tx][ty + 8 * i];
}

// ---- score partial: spart[nb][m] = sum_{n in nb-slice} tanh(q[b(m),n] + enc@w2) * v[n] ----
// GEMM C[16384,512] = enc_flat @ w2 via bf16 MFMA. Tile M=64 (one batch), N=128, K-step 64.
__global__ __launch_bounds__(256, 4) void k_score(
        const float* __restrict__ enc, const __bf16* __restrict__ w2t,
        const float* __restrict__ qq, const float* __restrict__ vvec,
        float* __restrict__ spart) {
    __shared__ bf16x8 Abuf[64][8];       // [row][granule ^ (row&7)]  8 KB
    __shared__ bf16x8 Bbuf[128][8];      // 16 KB
    __shared__ float qsv[128], vsv[128], wredL[2][64];
    const int tid = threadIdx.x;
    const int mb = blockIdx.x & 255, nb = blockIdx.x >> 8;
    const int m0 = mb * 64, n0 = nb * 128;
    const int l = tid & 63, wv = tid >> 6;
    const int wm = wv >> 1, wn = wv & 1;           // 2x2 waves, wave tile 32m x 64n
    const int ar = l & 15, agr = l >> 4;

    if (tid < 128) qsv[tid] = qq[(size_t)mb * AA + n0 + tid];
    else           vsv[tid - 128] = vvec[n0 + tid - 128];

    const int arow = tid >> 2, ag0 = (tid & 3) * 2;
    const float* aptr = enc + (size_t)(m0 + arow) * EE + ag0 * 8;
    const int brow = tid >> 1, bg0 = (tid & 1) * 4;
    const __bf16* bptr = w2t + (size_t)(n0 + brow) * EE + bg0 * 8;

    f32x4 acc[2][4];
    #pragma unroll
    for (int mi = 0; mi < 2; ++mi)
        #pragma unroll
        for (int ni = 0; ni < 4; ++ni)
            acc[mi][ni] = (f32x4){0.f, 0.f, 0.f, 0.f};

    float4 af[4];
    bf16x8 bstg[4];
    #pragma unroll
    for (int j = 0; j < 4; ++j) af[j] = *(const float4*)(aptr + j * 4);
    #pragma unroll
    for (int i = 0; i < 4; ++i) bstg[i] = *(const bf16x8*)(bptr + i * 8);

    const int NIT = EE / 64;   // 32
    for (int it = 0; it < NIT; ++it) {
        if (it > 0) __syncthreads();
        {
            bf16x8 pk;
            pk[0] = (__bf16)af[0].x; pk[1] = (__bf16)af[0].y; pk[2] = (__bf16)af[0].z; pk[3] = (__bf16)af[0].w;
            pk[4] = (__bf16)af[1].x; pk[5] = (__bf16)af[1].y; pk[6] = (__bf16)af[1].z; pk[7] = (__bf16)af[1].w;
            Abuf[arow][ag0 ^ (arow & 7)] = pk;
            pk[0] = (__bf16)af[2].x; pk[1] = (__bf16)af[2].y; pk[2] = (__bf16)af[2].z; pk[3] = (__bf16)af[2].w;
            pk[4] = (__bf16)af[3].x; pk[5] = (__bf16)af[3].y; pk[6] = (__bf16)af[3].z; pk[7] = (__bf16)af[3].w;
            Abuf[arow][(ag0 + 1) ^ (arow & 7)] = pk;
        }
        #pragma unroll
        for (int i = 0; i < 4; ++i)
            Bbuf[brow][(bg0 + i) ^ (brow & 7)] = bstg[i];
        if (it + 1 < NIT) {
            const int k1 = (it + 1) * 64;
            #pragma unroll
            for (int j = 0; j < 4; ++j) af[j] = *(const float4*)(aptr + k1 + j * 4);
            #pragma unroll
            for (int i = 0; i < 4; ++i) bstg[i] = *(const bf16x8*)(bptr + k1 + i * 8);
        }
        __syncthreads();
        #pragma unroll
        for (int ks = 0; ks < 2; ++ks) {
            bf16x8 afr[2], bfr[4];
            #pragma unroll
            for (int mi = 0; mi < 2; ++mi)
                afr[mi] = Abuf[wm * 32 + mi * 16 + ar][(ks * 4 + agr) ^ (ar & 7)];
            #pragma unroll
            for (int ni = 0; ni < 4; ++ni)
                bfr[ni] = Bbuf[wn * 64 + ni * 16 + ar][(ks * 4 + agr) ^ (ar & 7)];
            #pragma unroll
            for (int mi = 0; mi < 2; ++mi)
                #pragma unroll
                for (int ni = 0; ni < 4; ++ni)
                    acc[mi][ni] = __builtin_amdgcn_mfma_f32_16x16x32_bf16(afr[mi], bfr[ni], acc[mi][ni], 0, 0, 0);
        }
    }

    float sred[2][4];
    #pragma unroll
    for (int mi = 0; mi < 2; ++mi)
        #pragma unroll
        for (int r = 0; r < 4; ++r) sred[mi][r] = 0.f;
    #pragma unroll
    for (int ni = 0; ni < 4; ++ni) {
        const int col = wn * 64 + ni * 16 + ar;
        const float qa = qsv[col], va = vsv[col];
        #pragma unroll
        for (int mi = 0; mi < 2; ++mi)
            #pragma unroll
            for (int r = 0; r < 4; ++r)
                sred[mi][r] += tanhf(qa + acc[mi][ni][r]) * va;
    }
    #pragma unroll
    for (int mi = 0; mi < 2; ++mi)
        #pragma unroll
        for (int r = 0; r < 4; ++r) {
            #pragma unroll
            for (int off = 1; off < 16; off <<= 1)
                sred[mi][r] += __shfl_xor(sred[mi][r], off, 64);
        }
    if (ar == 0) {
        #pragma unroll
        for (int mi = 0; mi < 2; ++mi)
            #pragma unroll
            for (int r = 0; r < 4; ++r)
                wredL[wn][wm * 32 + mi * 16 + agr * 4 + r] = sred[mi][r];
    }
    __syncthreads();
    if (tid < 64)
        spart[(size_t)nb * MROWS + m0 + tid] = wredL[0][tid] + wredL[1][tid];
}

// ---------------- softmax over t (from 4 partials) + context = sum_t attn * enc ----------------
__global__ void k_context(const float* __restrict__ enc, const float* __restrict__ spart,
                          const float* __restrict__ bv, float* __restrict__ ctx) {
    __shared__ float attn[TT];
    const int b = blockIdx.y;
    const int tid = threadIdx.x;
    if (tid < 64) {
        const int m = b * TT + tid;
        float s = spart[m] + spart[MROWS + m] + spart[2 * MROWS + m] + spart[3 * MROWS + m] + bv[0];
        float mx = s;
        #pragma unroll
        for (int off = 1; off < 64; off <<= 1) mx = fmaxf(mx, __shfl_xor(mx, off, 64));
        float p = expf(s - mx);
        float sum = p;
        #pragma unroll
        for (int off = 1; off < 64; off <<= 1) sum += __shfl_xor(sum, off, 64);
        attn[tid] = p / sum;
    }
    __syncthreads();
    const int e = blockIdx.x * 1024 + tid * 4;
    const float* encb = enc + (size_t)b * TT * EE + e;
    float4 acc = {0.f, 0.f, 0.f, 0.f};
    #pragma unroll 4
    for (int t = 0; t < TT; ++t) {
        float a = attn[t];
        float4 ev = *(const float4*)&encb[(size_t)t * EE];
        acc.x = fmaf(a, ev.x, acc.x);
        acc.y = fmaf(a, ev.y, acc.y);
        acc.z = fmaf(a, ev.z, acc.z);
        acc.w = fmaf(a, ev.w, acc.w);
    }
    *(float4*)&ctx[(size_t)b * EE + e] = acc;
}

// ------- z = [ctx, emb[c], hidden] @ [wx; wh] via bf16 MFMA, K split 4 ways -------
#define ZKS 4
#define ZKC (KLSTM / ZKS)    // 704
#define ZNIT (ZKC / 32)      // 22
__global__ void k_z(const float* __restrict__ ctx, const float* __restrict__ emb,
                    const int* __restrict__ cidx, const float* __restrict__ hidden,
                    const __bf16* __restrict__ wt, float* __restrict__ zp) {
    __shared__ bf16x8 Abuf[32][ZKC / 8];   // [row][granule], granule ^= row&7 (45 KB)
    __shared__ int cbs[32];
    const int tid = threadIdx.x;
    const int l = tid & 63, wv = tid >> 6;
    const int b0  = blockIdx.y * 32;
    const int kc0 = blockIdx.z * ZKC;
    const int nw  = blockIdx.x * 256 + wv * 64;

    if (tid < 32) cbs[tid] = cidx[b0 + tid];
    __syncthreads();

    {
        const int srow = tid >> 3, g0 = tid & 7;
        const int bg = b0 + srow;
        const int erow = cbs[srow];
        #pragma unroll
        for (int i = 0; i < 11; ++i) {
            int g = g0 + 8 * i;
            int k = kc0 + g * 8;
            const float* src;
            if (k < EE)             src = &ctx[(size_t)bg * EE + k];
            else if (k < EE + EMBD) src = &emb[(size_t)erow * EMBD + (k - EE)];
            else                    src = &hidden[(size_t)bg * DD + (k - EE - EMBD)];
            float4 u0 = *(const float4*)src;
            float4 u1 = *(const float4*)(src + 4);
            bf16x8 pk;
            pk[0] = (__bf16)u0.x; pk[1] = (__bf16)u0.y; pk[2] = (__bf16)u0.z; pk[3] = (__bf16)u0.w;
            pk[4] = (__bf16)u1.x; pk[5] = (__bf16)u1.y; pk[6] = (__bf16)u1.z; pk[7] = (__bf16)u1.w;
            Abuf[srow][g ^ (srow & 7)] = pk;
        }
    }
    __syncthreads();

    const int ar = l & 15, agr = l >> 4;
    const __bf16* bbase = wt + (size_t)(nw + ar) * KLSTM + kc0 + agr * 8;

    f32x4 acc[2][4];
    #pragma unroll
    for (int mt = 0; mt < 2; ++mt)
        #pragma unroll
        for (int f = 0; f < 4; ++f)
            acc[mt][f] = (f32x4){0.f, 0.f, 0.f, 0.f};

    bf16x8 bA[4], bBv[4];
    #pragma unroll
    for (int f = 0; f < 4; ++f)
        bA[f] = *(const bf16x8*)(bbase + (size_t)f * 16 * KLSTM);

    for (int itp = 0; itp < ZNIT / 2; ++itp) {
        const int it0 = 2 * itp, it1 = 2 * itp + 1;
        #pragma unroll
        for (int f = 0; f < 4; ++f)
            bBv[f] = *(const bf16x8*)(bbase + (size_t)f * 16 * KLSTM + it1 * 32);
        {
            bf16x8 a0 = Abuf[ar][(it0 * 4 + agr) ^ (ar & 7)];
            bf16x8 a1 = Abuf[16 + ar][(it0 * 4 + agr) ^ (ar & 7)];
            #pragma unroll
            for (int f = 0; f < 4; ++f) {
                acc[0][f] = __builtin_amdgcn_mfma_f32_16x16x32_bf16(a0, bA[f], acc[0][f], 0, 0, 0);
                acc[1][f] = __builtin_amdgcn_mfma_f32_16x16x32_bf16(a1, bA[f], acc[1][f], 0, 0, 0);
            }
        }
        const int it2 = (it1 + 1 < ZNIT) ? it1 + 1 : it1;
        #pragma unroll
        for (int f = 0; f < 4; ++f)
            bA[f] = *(const bf16x8*)(bbase + (size_t)f * 16 * KLSTM + it2 * 32);
        {
            bf16x8 a0 = Abuf[ar][(it1 * 4 + agr) ^ (ar & 7)];
            bf16x8 a1 = Abuf[16 + ar][(it1 * 4 + agr) ^ (ar & 7)];
            #pragma unroll
            for (int f = 0; f < 4; ++f) {
                acc[0][f] = __builtin_amdgcn_mfma_f32_16x16x32_bf16(a0, bBv[f], acc[0][f], 0, 0, 0);
                acc[1][f] = __builtin_amdgcn_mfma_f32_16x16x32_bf16(a1, bBv[f], acc[1][f], 0, 0, 0);
            }
        }
    }

    float* zpo = zp + (size_t)blockIdx.z * BB * N4D;
    #pragma unroll
    for (int mt = 0; mt < 2; ++mt)
        #pragma unroll
        for (int f = 0; f < 4; ++f)
            #pragma unroll
            for (int r = 0; r < 4; ++r)
                zpo[(size_t)(b0 + mt * 16 + agr * 4 + r) * N4D + nw + f * 16 + ar] = acc[mt][f][r];
}

// ---------------- LSTM gates: sum K-split partials + bias, then activations ----------------
__global__ void k_gates(const float* __restrict__ zp, const float* __restrict__ carry,
                        const float* __restrict__ bl,
                        float* __restrict__ hout, float* __restrict__ cout) {
    const int b = blockIdx.x, tid = threadIdx.x;
    const size_t P = (size_t)BB * N4D;
    #pragma unroll
    for (int r = 0; r < 2; ++r) {
        int d = tid + r * 256;
        float zi = bl[d], zf = bl[DD + d], zg = bl[2 * DD + d], zo = bl[3 * DD + d];
        #pragma unroll
        for (int ks = 0; ks < ZKS; ++ks) {
            const float* zb = zp + ks * P + (size_t)b * N4D;
            zi += zb[d];
            zf += zb[DD + d];
            zg += zb[2 * DD + d];
            zo += zb[3 * DD + d];
        }
        float c = carry[(size_t)b * DD + d];
        float cn = sigf(zf) * c + sigf(zi) * tanhf(zg);
        float hn = sigf(zo) * tanhf(cn);
        cout[(size_t)b * DD + d] = cn;
        hout[(size_t)b * DD + d] = hn;
    }
}

// ---------------- logits = h_new @ wp + bp  via bf16 MFMA ----------------
// Tile 64M x 128N, K=512 (8 steps). grid flat 320: nb = id%80 (blocks sharing a
// wpt tile are 80 apart = same XCD), mb = id/80. Stores masked at col<VV.
__global__ __launch_bounds__(256, 4) void k_logits(
        const float* __restrict__ hnew, const __bf16* __restrict__ wpt,
        const float* __restrict__ bp, float* __restrict__ logits) {
    __shared__ bf16x8 Abuf[64][8];
    __shared__ bf16x8 Bbuf[128][8];
    __shared__ float bps[128];
    const int tid = threadIdx.x;
    const int nb = blockIdx.x % 80, mb = blockIdx.x / 80;
    const int m0 = mb * 64, n0 = nb * 128;
    const int l = tid & 63, wv = tid >> 6;
    const int wm = wv >> 1, wn = wv & 1;
    const int ar = l & 15, agr = l >> 4;

    if (tid < 128) {
        int j = n0 + tid;
        bps[tid] = (j < VV) ? bp[j] : 0.f;
    }

    const int arow = tid >> 2, ag0 = (tid & 3) * 2;
    const float* aptr = hnew + (size_t)(m0 + arow) * DD + ag0 * 8;
    const int brow = tid >> 1, bg0 = (tid & 1) * 4;
    const __bf16* bptr = wpt + (size_t)(n0 + brow) * DD + bg0 * 8;

    f32x4 acc[2][4];
    #pragma unroll
    for (int mi = 0; mi < 2; ++mi)
        #pragma unroll
        for (int ni = 0; ni < 4; ++ni)
            acc[mi][ni] = (f32x4){0.f, 0.f, 0.f, 0.f};

    float4 af[4];
    bf16x8 bstg[4];
    #pragma unroll
    for (int j = 0; j < 4; ++j) af[j] = *(const float4*)(aptr + j * 4);
    #pragma unroll
    for (int i = 0; i < 4; ++i) bstg[i] = *(const bf16x8*)(bptr + i * 8);

    const int NIT = DD / 64;   // 8
    for (int it = 0; it < NIT; ++it) {
        if (it > 0) __syncthreads();
        {
            bf16x8 pk;
            pk[0] = (__bf16)af[0].x; pk[1] = (__bf16)af[0].y; pk[2] = (__bf16)af[0].z; pk[3] = (__bf16)af[0].w;
            pk[4] = (__bf16)af[1].x; pk[5] = (__bf16)af[1].y; pk[6] = (__bf16)af[1].z; pk[7] = (__bf16)af[1].w;
            Abuf[arow][ag0 ^ (arow & 7)] = pk;
            pk[0] = (__bf16)af[2].x; pk[1] = (__bf16)af[2].y; pk[2] = (__bf16)af[2].z; pk[3] = (__bf16)af[2].w;
            pk[4] = (__bf16)af[3].x; pk[5] = (__bf16)af[3].y; pk[6] = (__bf16)af[3].z; pk[7] = (__bf16)af[3].w;
            Abuf[arow][(ag0 + 1) ^ (arow & 7)] = pk;
        }
        #pragma unroll
        for (int i = 0; i < 4; ++i)
            Bbuf[brow][(bg0 + i) ^ (brow & 7)] = bstg[i];
        if (it + 1 < NIT) {
            const int k1 = (it + 1) * 64;
            #pragma unroll
            for (int j = 0; j < 4; ++j) af[j] = *(const float4*)(aptr + k1 + j * 4);
            #pragma unroll
            for (int i = 0; i < 4; ++i) bstg[i] = *(const bf16x8*)(bptr + k1 + i * 8);
        }
        __syncthreads();
        #pragma unroll
        for (int ks = 0; ks < 2; ++ks) {
            bf16x8 afr[2], bfr[4];
            #pragma unroll
            for (int mi = 0; mi < 2; ++mi)
                afr[mi] = Abuf[wm * 32 + mi * 16 + ar][(ks * 4 + agr) ^ (ar & 7)];
            #pragma unroll
            for (int ni = 0; ni < 4; ++ni)
                bfr[ni] = Bbuf[wn * 64 + ni * 16 + ar][(ks * 4 + agr) ^ (ar & 7)];
            #pragma unroll
            for (int mi = 0; mi < 2; ++mi)
                #pragma unroll
                for (int ni = 0; ni < 4; ++ni)
                    acc[mi][ni] = __builtin_amdgcn_mfma_f32_16x16x32_bf16(afr[mi], bfr[ni], acc[mi][ni], 0, 0, 0);
        }
    }

    // store: row = m0 + wm*32 + mi*16 + agr*4 + r; col = n0 + wn*64 + ni*16 + ar
    #pragma unroll
    for (int mi = 0; mi < 2; ++mi)
        #pragma unroll
        for (int ni = 0; ni < 4; ++ni) {
            const int colL = wn * 64 + ni * 16 + ar;
            const int col = n0 + colL;
            if (col < VV) {
                const float bb = bps[colL];
                #pragma unroll
                for (int r = 0; r < 4; ++r) {
                    const int row = m0 + wm * 32 + mi * 16 + agr * 4 + r;
                    logits[(size_t)row * VV + col] = acc[mi][ni][r] + bb;
                }
            }
        }
}

extern "C" void kernel_launch(void* const* d_in, const int* in_sizes, int n_in,
                              void* d_out, int out_size, void* d_ws, size_t ws_size,
                              hipStream_t stream) {
    const int*   cidx   = (const int*)d_in[0];
    const float* hidden = (const float*)d_in[1];
    const float* carry  = (const float*)d_in[2];
    const float* enc    = (const float*)d_in[3];
    const float* emb    = (const float*)d_in[4];
    const float* w1     = (const float*)d_in[5];
    const float* b1     = (const float*)d_in[6];
    const float* w2     = (const float*)d_in[7];
    const float* b2     = (const float*)d_in[8];
    const float* vvec   = (const float*)d_in[9];
    const float* bv     = (const float*)d_in[10];
    const float* wx     = (const float*)d_in[11];
    const float* wh     = (const float*)d_in[12];
    const float* bl     = (const float*)d_in[13];
    const float* wp     = (const float*)d_in[14];
    const float* bp     = (const float*)d_in[15];

    float* out    = (float*)d_out;
    float* logits = out;
    float* hout   = out + (size_t)BB * VV;
    float* cout   = hout + (size_t)BB * DD;

    float* ws    = (float*)d_ws;
    float* qq    = ws;                          // B*A            = 131072 f32
    float* score = qq + (size_t)BB * AA;        // (layout keep)
    float* ctx   = score + (size_t)BB * TT;     // B*E            = 524288 f32
    float* zp    = ctx + (size_t)BB * EE;       // ZKS*B*4D       = 2097152 f32
    __bf16* wxh_t = (__bf16*)(zp + (size_t)ZKS * BB * N4D);   // 2048*2816 bf16 = 11.5 MB
    float* spart = (float*)(wxh_t + (size_t)N4D * KLSTM);     // 4*16384 f32 = 256 KB
    __bf16* wpt  = (__bf16*)(spart + (size_t)4 * MROWS);      // 10240*512 bf16 = 10.5 MB
    // w2t (512x2048 bf16 = 2 MB) aliases ctx: consumed by k_score BEFORE k_context writes ctx
    __bf16* w2t  = (__bf16*)ctx;

    hipLaunchKernelGGL(k_w2t,     dim3(EE / 32, AA / 32),    dim3(32, 8), 0, stream, w2, w2t);
    hipLaunchKernelGGL(k_wxht,    dim3(KLSTM / 32, N4D / 32), dim3(32, 8), 0, stream, wx, wh, wxh_t);
    hipLaunchKernelGGL(k_wpt,     dim3(DD / 32, VPAD / 32),  dim3(32, 8), 0, stream, wp, wpt);
    hipLaunchKernelGGL(k_q,       dim3(BB),                  dim3(256), 0, stream, hidden, w1, b1, b2, qq);
    hipLaunchKernelGGL(k_score,   dim3(1024),                dim3(256), 0, stream, enc, w2t, qq, vvec, spart);
    hipLaunchKernelGGL(k_context, dim3(2, BB),               dim3(256), 0, stream, enc, spart, bv, ctx);
    hipLaunchKernelGGL(k_z,       dim3(N4D / 256, BB / 32, ZKS), dim3(256), 0, stream, ctx, emb, cidx, hidden, wxh_t, zp);
    hipLaunchKernelGGL(k_gates,   dim3(BB),                  dim3(256), 0, stream, zp, carry, bl, hout, cout);
    hipLaunchKernelGGL(k_logits,  dim3(320),                 dim3(256), 0, stream, hout, wpt, bp, logits);
}

// Round 8
// 207.514 us; speedup vs baseline: 2.3055x; 1.0029x over previous
//
#include <hip/hip_runtime.h>
#include <hip/hip_bf16.h>
#include <math.h>

#define BB 256
#define TT 64
#define EE 2048
#define DD 512
#define AA 512
#define VV 10000
#define VPAD 10240               // 80 * 128
#define EMBD 256
#define KLSTM (EE + EMBD + DD)   // 2816
#define N4D (4 * DD)             // 2048
#define MROWS (BB * TT)          // 16384

using bf16x8 = __attribute__((ext_vector_type(8))) __bf16;
using f32x4  = __attribute__((ext_vector_type(4))) float;

__device__ __forceinline__ float sigf(float x) { return 1.f / (1.f + expf(-x)); }

// ---------------- q = hidden @ w1 + b1 + b2 (fold both biases) ----------------
__global__ void k_q(const float* __restrict__ hidden, const float* __restrict__ w1,
                    const float* __restrict__ b1, const float* __restrict__ b2,
                    float* __restrict__ qq) {
    __shared__ float hs[DD];
    const int b = blockIdx.x, tid = threadIdx.x;
    {
        float2 hv = *(const float2*)&hidden[(size_t)b * DD + 2 * tid];
        hs[2 * tid] = hv.x; hs[2 * tid + 1] = hv.y;
    }
    __syncthreads();
    const int a0 = 2 * tid;
    float2 acc = {0.f, 0.f};
    #pragma unroll 4
    for (int k = 0; k < DD; ++k) {
        float2 w = *(const float2*)&w1[(size_t)k * AA + a0];
        float h = hs[k];
        acc.x = fmaf(h, w.x, acc.x);
        acc.y = fmaf(h, w.y, acc.y);
    }
    qq[(size_t)b * AA + a0]     = acc.x + b1[a0]     + b2[a0];
    qq[(size_t)b * AA + a0 + 1] = acc.y + b1[a0 + 1] + b2[a0 + 1];
}

// ---------------- w2t[n][k] = bf16(w2[k][n])  (2048x512 -> 512x2048) ----------------
__global__ void k_w2t(const float* __restrict__ w2, __bf16* __restrict__ w2t) {
    __shared__ float t[32][33];
    const int k0 = blockIdx.x * 32, n0 = blockIdx.y * 32;
    const int tx = threadIdx.x, ty = threadIdx.y;   // block (32,8)
    #pragma unroll
    for (int i = 0; i < 4; ++i)
        t[ty + 8 * i][tx] = w2[(size_t)(k0 + ty + 8 * i) * AA + n0 + tx];
    __syncthreads();
    #pragma unroll
    for (int i = 0; i < 4; ++i)
        w2t[(size_t)(n0 + ty + 8 * i) * EE + k0 + tx] = (__bf16)t[tx][ty + 8 * i];
}

// ------- wxh_t[n][k] = bf16( k<2304 ? wx[k][n] : wh[k-2304][n] ), n<2048, k<2816 -------
__global__ void k_wxht(const float* __restrict__ wx, const float* __restrict__ wh,
                       __bf16* __restrict__ wt) {
    __shared__ float t[32][33];
    const int k0 = blockIdx.x * 32, n0 = blockIdx.y * 32;
    const int tx = threadIdx.x, ty = threadIdx.y;   // block (32,8)
    #pragma unroll
    for (int i = 0; i < 4; ++i) {
        int k = k0 + ty + 8 * i;
        const float* wrow = (k < EE + EMBD) ? &wx[(size_t)k * N4D] : &wh[(size_t)(k - EE - EMBD) * N4D];
        t[ty + 8 * i][tx] = wrow[n0 + tx];
    }
    __syncthreads();
    #pragma unroll
    for (int i = 0; i < 4; ++i)
        wt[(size_t)(n0 + ty + 8 * i) * KLSTM + k0 + tx] = (__bf16)t[tx][ty + 8 * i];
}

// ------- wpt[n][k] = bf16(wp[k][n]), n < VPAD (tail rows clamp-read, masked at use) -------
__global__ void k_wpt(const float* __restrict__ wp, __bf16* __restrict__ wpt) {
    __shared__ float t[32][33];
    const int k0 = blockIdx.x * 32, n0 = blockIdx.y * 32;
    const int tx = threadIdx.x, ty = threadIdx.y;   // block (32,8)
    #pragma unroll
    for (int i = 0; i < 4; ++i) {
        int n = n0 + tx;
        t[ty + 8 * i][tx] = wp[(size_t)(k0 + ty + 8 * i) * VV + (n < VV ? n : VV - 1)];
    }
    __syncthreads();
    #pragma unroll
    for (int i = 0; i < 4; ++i)
        wpt[(size_t)(n0 + ty + 8 * i) * DD + k0 + tx] = (__bf16)t[tx][ty + 8 * i];
}

// ---- fused attention scores + softmax: attnG[b][t] ----
// One block per b (grid 256 = 1/CU), 512 threads = 8 waves (2/SIMD). Each wave
// owns a 64-col n-slice of N=512; M=64 rows (all t of this b). enc read ONCE,
// staged f32->bf16 into swizzled dbuf LDS. B (w2t, 2MB, XCD-L2-resident) read
// direct from L2. Epilogue: tanh(q+s).v, lane reduce, cross-wave reduce,
// 64-lane softmax -> attn weights.
__global__ __launch_bounds__(512, 1) void k_attn(
        const float* __restrict__ enc, const __bf16* __restrict__ w2t,
        const float* __restrict__ qq, const float* __restrict__ vvec,
        const float* __restrict__ bv, float* __restrict__ attnG) {
    __shared__ bf16x8 Abuf[2][64][8];     // 16 KB, [buf][row][granule ^ (row&7)]
    __shared__ float qs[AA], vs[AA];
    __shared__ float wred[8][64];
    const int b = blockIdx.x;
    const int tid = threadIdx.x;          // 0..511
    const int l = tid & 63, wv = tid >> 6;
    const int n0w = wv * 64;
    const int ar = l & 15, agr = l >> 4;

    qs[tid] = qq[(size_t)b * AA + tid];
    vs[tid] = vvec[tid];

    // A staging: 8 threads/row, 32 B each (granule = 8 f32 -> bf16x8)
    const int srow = tid >> 3, skseg = tid & 7;
    const float* encrow = enc + ((size_t)b * TT + srow) * EE + skseg * 8;
    const int sg = skseg ^ (srow & 7);

    const __bf16* bbase = w2t + (size_t)(n0w + ar) * EE + agr * 8;

    f32x4 acc[4][4];
    #pragma unroll
    for (int mi = 0; mi < 4; ++mi)
        #pragma unroll
        for (int ni = 0; ni < 4; ++ni)
            acc[mi][ni] = (f32x4){0.f, 0.f, 0.f, 0.f};

    {   // prologue: tile 0
        float4 u0 = *(const float4*)(encrow);
        float4 u1 = *(const float4*)(encrow + 4);
        bf16x8 pk;
        pk[0] = (__bf16)u0.x; pk[1] = (__bf16)u0.y; pk[2] = (__bf16)u0.z; pk[3] = (__bf16)u0.w;
        pk[4] = (__bf16)u1.x; pk[5] = (__bf16)u1.y; pk[6] = (__bf16)u1.z; pk[7] = (__bf16)u1.w;
        Abuf[0][srow][sg] = pk;
    }
    __syncthreads();

    const int NIT = EE / 64;   // 32
    for (int it = 0; it < NIT; ++it) {
        const int cur = it & 1;
        float4 p0, p1;
        const bool more = (it + 1 < NIT);
        if (more) {
            p0 = *(const float4*)(encrow + (it + 1) * 64);
            p1 = *(const float4*)(encrow + (it + 1) * 64 + 4);
        }
        #pragma unroll
        for (int ks = 0; ks < 2; ++ks) {
            bf16x8 bfr[4], afr[4];
            #pragma unroll
            for (int ni = 0; ni < 4; ++ni)
                bfr[ni] = *(const bf16x8*)(bbase + (size_t)(ni * 16) * EE + it * 64 + ks * 32);
            #pragma unroll
            for (int mi = 0; mi < 4; ++mi)
                afr[mi] = Abuf[cur][mi * 16 + ar][(ks * 4 + agr) ^ (ar & 7)];
            #pragma unroll
            for (int mi = 0; mi < 4; ++mi)
                #pragma unroll
                for (int ni = 0; ni < 4; ++ni)
                    acc[mi][ni] = __builtin_amdgcn_mfma_f32_16x16x32_bf16(afr[mi], bfr[ni], acc[mi][ni], 0, 0, 0);
        }
        if (more) {
            bf16x8 pk;
            pk[0] = (__bf16)p0.x; pk[1] = (__bf16)p0.y; pk[2] = (__bf16)p0.z; pk[3] = (__bf16)p0.w;
            pk[4] = (__bf16)p1.x; pk[5] = (__bf16)p1.y; pk[6] = (__bf16)p1.z; pk[7] = (__bf16)p1.w;
            Abuf[cur ^ 1][srow][sg] = pk;
        }
        __syncthreads();
    }

    // epilogue: tanh(q + s) * v, reduce over this wave's 64 n-cols
    float sred[4][4];
    #pragma unroll
    for (int mi = 0; mi < 4; ++mi)
        #pragma unroll
        for (int r = 0; r < 4; ++r) sred[mi][r] = 0.f;
    #pragma unroll
    for (int ni = 0; ni < 4; ++ni) {
        const int col = n0w + ni * 16 + ar;
        const float qa = qs[col], va = vs[col];
        #pragma unroll
        for (int mi = 0; mi < 4; ++mi)
            #pragma unroll
            for (int r = 0; r < 4; ++r)
                sred[mi][r] += tanhf(qa + acc[mi][ni][r]) * va;
    }
    #pragma unroll
    for (int mi = 0; mi < 4; ++mi)
        #pragma unroll
        for (int r = 0; r < 4; ++r) {
            #pragma unroll
            for (int off = 1; off < 16; off <<= 1)
                sred[mi][r] += __shfl_xor(sred[mi][r], off, 64);
        }
    if (ar == 0) {
        #pragma unroll
        for (int mi = 0; mi < 4; ++mi)
            #pragma unroll
            for (int r = 0; r < 4; ++r)
                wred[wv][mi * 16 + agr * 4 + r] = sred[mi][r];
    }
    __syncthreads();
    if (tid < 64) {
        float s = bv[0];
        #pragma unroll
        for (int w = 0; w < 8; ++w) s += wred[w][tid];
        float mx = s;
        #pragma unroll
        for (int off = 1; off < 64; off <<= 1) mx = fmaxf(mx, __shfl_xor(mx, off, 64));
        float p = expf(s - mx);
        float sum = p;
        #pragma unroll
        for (int off = 1; off < 64; off <<= 1) sum += __shfl_xor(sum, off, 64);
        attnG[(size_t)b * TT + tid] = p / sum;
    }
}

// ---------------- context = sum_t attn[t] * enc[b,t,:] ----------------
__global__ void k_context(const float* __restrict__ enc, const float* __restrict__ attnG,
                          float* __restrict__ ctx) {
    __shared__ float attn[TT];
    const int b = blockIdx.y;
    const int tid = threadIdx.x;
    if (tid < 64) attn[tid] = attnG[(size_t)b * TT + tid];
    __syncthreads();
    const int e = blockIdx.x * 1024 + tid * 4;
    const float* encb = enc + (size_t)b * TT * EE + e;
    float4 acc = {0.f, 0.f, 0.f, 0.f};
    #pragma unroll 4
    for (int t = 0; t < TT; ++t) {
        float a = attn[t];
        float4 ev = *(const float4*)&encb[(size_t)t * EE];
        acc.x = fmaf(a, ev.x, acc.x);
        acc.y = fmaf(a, ev.y, acc.y);
        acc.z = fmaf(a, ev.z, acc.z);
        acc.w = fmaf(a, ev.w, acc.w);
    }
    *(float4*)&ctx[(size_t)b * EE + e] = acc;
}

// ------- z = [ctx, emb[c], hidden] @ [wx; wh] via bf16 MFMA, K split 4 ways -------
#define ZKS 4
#define ZKC (KLSTM / ZKS)    // 704
#define ZNIT (ZKC / 32)      // 22
__global__ void k_z(const float* __restrict__ ctx, const float* __restrict__ emb,
                    const int* __restrict__ cidx, const float* __restrict__ hidden,
                    const __bf16* __restrict__ wt, float* __restrict__ zp) {
    __shared__ bf16x8 Abuf[32][ZKC / 8];   // [row][granule], granule ^= row&7 (45 KB)
    __shared__ int cbs[32];
    const int tid = threadIdx.x;
    const int l = tid & 63, wv = tid >> 6;
    const int b0  = blockIdx.y * 32;
    const int kc0 = blockIdx.z * ZKC;
    const int nw  = blockIdx.x * 256 + wv * 64;

    if (tid < 32) cbs[tid] = cidx[b0 + tid];
    __syncthreads();

    {
        const int srow = tid >> 3, g0 = tid & 7;
        const int bg = b0 + srow;
        const int erow = cbs[srow];
        #pragma unroll
        for (int i = 0; i < 11; ++i) {
            int g = g0 + 8 * i;
            int k = kc0 + g * 8;
            const float* src;
            if (k < EE)             src = &ctx[(size_t)bg * EE + k];
            else if (k < EE + EMBD) src = &emb[(size_t)erow * EMBD + (k - EE)];
            else                    src = &hidden[(size_t)bg * DD + (k - EE - EMBD)];
            float4 u0 = *(const float4*)src;
            float4 u1 = *(const float4*)(src + 4);
            bf16x8 pk;
            pk[0] = (__bf16)u0.x; pk[1] = (__bf16)u0.y; pk[2] = (__bf16)u0.z; pk[3] = (__bf16)u0.w;
            pk[4] = (__bf16)u1.x; pk[5] = (__bf16)u1.y; pk[6] = (__bf16)u1.z; pk[7] = (__bf16)u1.w;
            Abuf[srow][g ^ (srow & 7)] = pk;
        }
    }
    __syncthreads();

    const int ar = l & 15, agr = l >> 4;
    const __bf16* bbase = wt + (size_t)(nw + ar) * KLSTM + kc0 + agr * 8;

    f32x4 acc[2][4];
    #pragma unroll
    for (int mt = 0; mt < 2; ++mt)
        #pragma unroll
        for (int f = 0; f < 4; ++f)
            acc[mt][f] = (f32x4){0.f, 0.f, 0.f, 0.f};

    bf16x8 bA[4], bBv[4];
    #pragma unroll
    for (int f = 0; f < 4; ++f)
        bA[f] = *(const bf16x8*)(bbase + (size_t)f * 16 * KLSTM);

    for (int itp = 0; itp < ZNIT / 2; ++itp) {
        const int it0 = 2 * itp, it1 = 2 * itp + 1;
        #pragma unroll
        for (int f = 0; f < 4; ++f)
            bBv[f] = *(const bf16x8*)(bbase + (size_t)f * 16 * KLSTM + it1 * 32);
        {
            bf16x8 a0 = Abuf[ar][(it0 * 4 + agr) ^ (ar & 7)];
            bf16x8 a1 = Abuf[16 + ar][(it0 * 4 + agr) ^ (ar & 7)];
            #pragma unroll
            for (int f = 0; f < 4; ++f) {
                acc[0][f] = __builtin_amdgcn_mfma_f32_16x16x32_bf16(a0, bA[f], acc[0][f], 0, 0, 0);
                acc[1][f] = __builtin_amdgcn_mfma_f32_16x16x32_bf16(a1, bA[f], acc[1][f], 0, 0, 0);
            }
        }
        const int it2 = (it1 + 1 < ZNIT) ? it1 + 1 : it1;
        #pragma unroll
        for (int f = 0; f < 4; ++f)
            bA[f] = *(const bf16x8*)(bbase + (size_t)f * 16 * KLSTM + it2 * 32);
        {
            bf16x8 a0 = Abuf[ar][(it1 * 4 + agr) ^ (ar & 7)];
            bf16x8 a1 = Abuf[16 + ar][(it1 * 4 + agr) ^ (ar & 7)];
            #pragma unroll
            for (int f = 0; f < 4; ++f) {
                acc[0][f] = __builtin_amdgcn_mfma_f32_16x16x32_bf16(a0, bBv[f], acc[0][f], 0, 0, 0);
                acc[1][f] = __builtin_amdgcn_mfma_f32_16x16x32_bf16(a1, bBv[f], acc[1][f], 0, 0, 0);
            }
        }
    }

    float* zpo = zp + (size_t)blockIdx.z * BB * N4D;
    #pragma unroll
    for (int mt = 0; mt < 2; ++mt)
        #pragma unroll
        for (int f = 0; f < 4; ++f)
            #pragma unroll
            for (int r = 0; r < 4; ++r)
                zpo[(size_t)(b0 + mt * 16 + agr * 4 + r) * N4D + nw + f * 16 + ar] = acc[mt][f][r];
}

// ---------------- LSTM gates: sum K-split partials + bias, then activations ----------------
__global__ void k_gates(const float* __restrict__ zp, const float* __restrict__ carry,
                        const float* __restrict__ bl,
                        float* __restrict__ hout, float* __restrict__ cout) {
    const int b = blockIdx.x, tid = threadIdx.x;
    const size_t P = (size_t)BB * N4D;
    #pragma unroll
    for (int r = 0; r < 2; ++r) {
        int d = tid + r * 256;
        float zi = bl[d], zf = bl[DD + d], zg = bl[2 * DD + d], zo = bl[3 * DD + d];
        #pragma unroll
        for (int ks = 0; ks < ZKS; ++ks) {
            const float* zb = zp + ks * P + (size_t)b * N4D;
            zi += zb[d];
            zf += zb[DD + d];
            zg += zb[2 * DD + d];
            zo += zb[3 * DD + d];
        }
        float c = carry[(size_t)b * DD + d];
        float cn = sigf(zf) * c + sigf(zi) * tanhf(zg);
        float hn = sigf(zo) * tanhf(cn);
        cout[(size_t)b * DD + d] = cn;
        hout[(size_t)b * DD + d] = hn;
    }
}

// ---------------- logits = h_new @ wp + bp  via bf16 MFMA ----------------
__global__ __launch_bounds__(256, 4) void k_logits(
        const float* __restrict__ hnew, const __bf16* __restrict__ wpt,
        const float* __restrict__ bp, float* __restrict__ logits) {
    __shared__ bf16x8 Abuf[64][8];
    __shared__ bf16x8 Bbuf[128][8];
    __shared__ float bps[128];
    const int tid = threadIdx.x;
    const int nb = blockIdx.x % 80, mb = blockIdx.x / 80;
    const int m0 = mb * 64, n0 = nb * 128;
    const int l = tid & 63, wv = tid >> 6;
    const int wm = wv >> 1, wn = wv & 1;
    const int ar = l & 15, agr = l >> 4;

    if (tid < 128) {
        int j = n0 + tid;
        bps[tid] = (j < VV) ? bp[j] : 0.f;
    }

    const int arow = tid >> 2, ag0 = (tid & 3) * 2;
    const float* aptr = hnew + (size_t)(m0 + arow) * DD + ag0 * 8;
    const int brow = tid >> 1, bg0 = (tid & 1) * 4;
    const __bf16* bptr = wpt + (size_t)(n0 + brow) * DD + bg0 * 8;

    f32x4 acc[2][4];
    #pragma unroll
    for (int mi = 0; mi < 2; ++mi)
        #pragma unroll
        for (int ni = 0; ni < 4; ++ni)
            acc[mi][ni] = (f32x4){0.f, 0.f, 0.f, 0.f};

    float4 af[4];
    bf16x8 bstg[4];
    #pragma unroll
    for (int j = 0; j < 4; ++j) af[j] = *(const float4*)(aptr + j * 4);
    #pragma unroll
    for (int i = 0; i < 4; ++i) bstg[i] = *(const bf16x8*)(bptr + i * 8);

    const int NIT = DD / 64;   // 8
    for (int it = 0; it < NIT; ++it) {
        if (it > 0) __syncthreads();
        {
            bf16x8 pk;
            pk[0] = (__bf16)af[0].x; pk[1] = (__bf16)af[0].y; pk[2] = (__bf16)af[0].z; pk[3] = (__bf16)af[0].w;
            pk[4] = (__bf16)af[1].x; pk[5] = (__bf16)af[1].y; pk[6] = (__bf16)af[1].z; pk[7] = (__bf16)af[1].w;
            Abuf[arow][ag0 ^ (arow & 7)] = pk;
            pk[0] = (__bf16)af[2].x; pk[1] = (__bf16)af[2].y; pk[2] = (__bf16)af[2].z; pk[3] = (__bf16)af[2].w;
            pk[4] = (__bf16)af[3].x; pk[5] = (__bf16)af[3].y; pk[6] = (__bf16)af[3].z; pk[7] = (__bf16)af[3].w;
            Abuf[arow][(ag0 + 1) ^ (arow & 7)] = pk;
        }
        #pragma unroll
        for (int i = 0; i < 4; ++i)
            Bbuf[brow][(bg0 + i) ^ (brow & 7)] = bstg[i];
        if (it + 1 < NIT) {
            const int k1 = (it + 1) * 64;
            #pragma unroll
            for (int j = 0; j < 4; ++j) af[j] = *(const float4*)(aptr + k1 + j * 4);
            #pragma unroll
            for (int i = 0; i < 4; ++i) bstg[i] = *(const bf16x8*)(bptr + k1 + i * 8);
        }
        __syncthreads();
        #pragma unroll
        for (int ks = 0; ks < 2; ++ks) {
            bf16x8 afr[2], bfr[4];
            #pragma unroll
            for (int mi = 0; mi < 2; ++mi)
                afr[mi] = Abuf[wm * 32 + mi * 16 + ar][(ks * 4 + agr) ^ (ar & 7)];
            #pragma unroll
            for (int ni = 0; ni < 4; ++ni)
                bfr[ni] = Bbuf[wn * 64 + ni * 16 + ar][(ks * 4 + agr) ^ (ar & 7)];
            #pragma unroll
            for (int mi = 0; mi < 2; ++mi)
                #pragma unroll
                for (int ni = 0; ni < 4; ++ni)
                    acc[mi][ni] = __builtin_amdgcn_mfma_f32_16x16x32_bf16(afr[mi], bfr[ni], acc[mi][ni], 0, 0, 0);
        }
    }

    #pragma unroll
    for (int mi = 0; mi < 2; ++mi)
        #pragma unroll
        for (int ni = 0; ni < 4; ++ni) {
            const int colL = wn * 64 + ni * 16 + ar;
            const int col = n0 + colL;
            if (col < VV) {
                const float bb = bps[colL];
                #pragma unroll
                for (int r = 0; r < 4; ++r) {
                    const int row = m0 + wm * 32 + mi * 16 + agr * 4 + r;
                    logits[(size_t)row * VV + col] = acc[mi][ni][r] + bb;
                }
            }
        }
}

extern "C" void kernel_launch(void* const* d_in, const int* in_sizes, int n_in,
                              void* d_out, int out_size, void* d_ws, size_t ws_size,
                              hipStream_t stream) {
    const int*   cidx   = (const int*)d_in[0];
    const float* hidden = (const float*)d_in[1];
    const float* carry  = (const float*)d_in[2];
    const float* enc    = (const float*)d_in[3];
    const float* emb    = (const float*)d_in[4];
    const float* w1     = (const float*)d_in[5];
    const float* b1     = (const float*)d_in[6];
    const float* w2     = (const float*)d_in[7];
    const float* b2     = (const float*)d_in[8];
    const float* vvec   = (const float*)d_in[9];
    const float* bv     = (const float*)d_in[10];
    const float* wx     = (const float*)d_in[11];
    const float* wh     = (const float*)d_in[12];
    const float* bl     = (const float*)d_in[13];
    const float* wp     = (const float*)d_in[14];
    const float* bp     = (const float*)d_in[15];

    float* out    = (float*)d_out;
    float* logits = out;
    float* hout   = out + (size_t)BB * VV;
    float* cout   = hout + (size_t)BB * DD;

    float* ws    = (float*)d_ws;
    float* qq    = ws;                          // B*A     = 131072 f32
    float* attnG = qq + (size_t)BB * AA;        // B*T     = 16384 f32
    float* ctx   = attnG + (size_t)BB * TT;     // B*E     = 524288 f32
    float* zp    = ctx + (size_t)BB * EE;       // ZKS*B*4D = 2097152 f32
    __bf16* wxh_t = (__bf16*)(zp + (size_t)ZKS * BB * N4D);   // 2048*2816 bf16 = 11.5 MB
    __bf16* wpt  = (__bf16*)(wxh_t + (size_t)N4D * KLSTM);    // 10240*512 bf16 = 10.5 MB
    // w2t (512x2048 bf16 = 2 MB) aliases ctx: consumed by k_attn BEFORE k_context writes ctx
    __bf16* w2t  = (__bf16*)ctx;

    hipLaunchKernelGGL(k_w2t,     dim3(EE / 32, AA / 32),    dim3(32, 8), 0, stream, w2, w2t);
    hipLaunchKernelGGL(k_wxht,    dim3(KLSTM / 32, N4D / 32), dim3(32, 8), 0, stream, wx, wh, wxh_t);
    hipLaunchKernelGGL(k_wpt,     dim3(DD / 32, VPAD / 32),  dim3(32, 8), 0, stream, wp, wpt);
    hipLaunchKernelGGL(k_q,       dim3(BB),                  dim3(256), 0, stream, hidden, w1, b1, b2, qq);
    hipLaunchKernelGGL(k_attn,    dim3(BB),                  dim3(512), 0, stream, enc, w2t, qq, vvec, bv, attnG);
    hipLaunchKernelGGL(k_context, dim3(2, BB),               dim3(256), 0, stream, enc, attnG, ctx);
    hipLaunchKernelGGL(k_z,       dim3(N4D / 256, BB / 32, ZKS), dim3(256), 0, stream, ctx, emb, cidx, hidden, wxh_t, zp);
    hipLaunchKernelGGL(k_gates,   dim3(BB),                  dim3(256), 0, stream, zp, carry, bl, hout, cout);
    hipLaunchKernelGGL(k_logits,  dim3(320),                 dim3(256), 0, stream, hout, wpt, bp, logits);
}

// Round 9
// 195.074 us; speedup vs baseline: 2.4525x; 1.0638x over previous
//
#include <hip/hip_runtime.h>
#include <hip/hip_bf16.h>
#include <math.h>

#define BB 256
#define TT 64
#define EE 2048
#define DD 512
#define AA 512
#define VV 10000
#define VPAD 10240               // 80 * 128
#define EMBD 256
#define KLSTM (EE + EMBD + DD)   // 2816
#define N4D (4 * DD)             // 2048
#define MROWS (BB * TT)          // 16384

using bf16x8 = __attribute__((ext_vector_type(8))) __bf16;
using f32x4  = __attribute__((ext_vector_type(4))) float;

__device__ __forceinline__ float sigf(float x) { return 1.f / (1.f + expf(-x)); }

// ---------------- q = hidden @ w1 + b1 + b2 (fold both biases) ----------------
__global__ void k_q(const float* __restrict__ hidden, const float* __restrict__ w1,
                    const float* __restrict__ b1, const float* __restrict__ b2,
                    float* __restrict__ qq) {
    __shared__ float hs[DD];
    const int b = blockIdx.x, tid = threadIdx.x;
    {
        float2 hv = *(const float2*)&hidden[(size_t)b * DD + 2 * tid];
        hs[2 * tid] = hv.x; hs[2 * tid + 1] = hv.y;
    }
    __syncthreads();
    const int a0 = 2 * tid;
    float2 acc = {0.f, 0.f};
    #pragma unroll 4
    for (int k = 0; k < DD; ++k) {
        float2 w = *(const float2*)&w1[(size_t)k * AA + a0];
        float h = hs[k];
        acc.x = fmaf(h, w.x, acc.x);
        acc.y = fmaf(h, w.y, acc.y);
    }
    qq[(size_t)b * AA + a0]     = acc.x + b1[a0]     + b2[a0];
    qq[(size_t)b * AA + a0 + 1] = acc.y + b1[a0 + 1] + b2[a0 + 1];
}

// ---------------- w2t[n][k] = bf16(w2[k][n])  (2048x512 -> 512x2048) ----------------
__global__ void k_w2t(const float* __restrict__ w2, __bf16* __restrict__ w2t) {
    __shared__ float t[32][33];
    const int k0 = blockIdx.x * 32, n0 = blockIdx.y * 32;
    const int tx = threadIdx.x, ty = threadIdx.y;   // block (32,8)
    #pragma unroll
    for (int i = 0; i < 4; ++i)
        t[ty + 8 * i][tx] = w2[(size_t)(k0 + ty + 8 * i) * AA + n0 + tx];
    __syncthreads();
    #pragma unroll
    for (int i = 0; i < 4; ++i)
        w2t[(size_t)(n0 + ty + 8 * i) * EE + k0 + tx] = (__bf16)t[tx][ty + 8 * i];
}

// ------- wxh_t[n][k] = bf16( k<2304 ? wx[k][n] : wh[k-2304][n] ), n<2048, k<2816 -------
__global__ void k_wxht(const float* __restrict__ wx, const float* __restrict__ wh,
                       __bf16* __restrict__ wt) {
    __shared__ float t[32][33];
    const int k0 = blockIdx.x * 32, n0 = blockIdx.y * 32;
    const int tx = threadIdx.x, ty = threadIdx.y;   // block (32,8)
    #pragma unroll
    for (int i = 0; i < 4; ++i) {
        int k = k0 + ty + 8 * i;
        const float* wrow = (k < EE + EMBD) ? &wx[(size_t)k * N4D] : &wh[(size_t)(k - EE - EMBD) * N4D];
        t[ty + 8 * i][tx] = wrow[n0 + tx];
    }
    __syncthreads();
    #pragma unroll
    for (int i = 0; i < 4; ++i)
        wt[(size_t)(n0 + ty + 8 * i) * KLSTM + k0 + tx] = (__bf16)t[tx][ty + 8 * i];
}

// ------- wpt[n][k] = bf16(wp[k][n]), n < VPAD (tail rows clamp-read, masked at use) -------
__global__ void k_wpt(const float* __restrict__ wp, __bf16* __restrict__ wpt) {
    __shared__ float t[32][33];
    const int k0 = blockIdx.x * 32, n0 = blockIdx.y * 32;
    const int tx = threadIdx.x, ty = threadIdx.y;   // block (32,8)
    #pragma unroll
    for (int i = 0; i < 4; ++i) {
        int n = n0 + tx;
        t[ty + 8 * i][tx] = wp[(size_t)(k0 + ty + 8 * i) * VV + (n < VV ? n : VV - 1)];
    }
    __syncthreads();
    #pragma unroll
    for (int i = 0; i < 4; ++i)
        wpt[(size_t)(n0 + ty + 8 * i) * DD + k0 + tx] = (__bf16)t[tx][ty + 8 * i];
}

// ---- fused attention scores + softmax: attnG[b][t] ----
// One block per b, 512 threads = 8 waves. Wave owns a 64-col n-slice of N=512;
// M=64 rows. enc streamed once through swizzled dbuf LDS; B (w2t, L2-resident)
// register ping-pong prefetched ONE ITERATION AHEAD (k_z pattern) so MFMA never
// waits on an L2 round-trip.
__global__ __launch_bounds__(512, 1) void k_attn(
        const float* __restrict__ enc, const __bf16* __restrict__ w2t,
        const float* __restrict__ qq, const float* __restrict__ vvec,
        const float* __restrict__ bv, float* __restrict__ attnG) {
    __shared__ bf16x8 Abuf[2][64][8];     // 16 KB, [buf][row][granule ^ (row&7)]
    __shared__ float qs[AA], vs[AA];
    __shared__ float wred[8][64];
    const int b = blockIdx.x;
    const int tid = threadIdx.x;          // 0..511
    const int l = tid & 63, wv = tid >> 6;
    const int n0w = wv * 64;
    const int ar = l & 15, agr = l >> 4;

    qs[tid] = qq[(size_t)b * AA + tid];
    vs[tid] = vvec[tid];

    const int srow = tid >> 3, skseg = tid & 7;
    const float* encrow = enc + ((size_t)b * TT + srow) * EE + skseg * 8;
    const int sg = skseg ^ (srow & 7);

    const __bf16* bbase = w2t + (size_t)(n0w + ar) * EE + agr * 8;

    f32x4 acc[4][4];
    #pragma unroll
    for (int mi = 0; mi < 4; ++mi)
        #pragma unroll
        for (int ni = 0; ni < 4; ++ni)
            acc[mi][ni] = (f32x4){0.f, 0.f, 0.f, 0.f};

    {   // prologue: A tile 0 -> Abuf[0]
        float4 u0 = *(const float4*)(encrow);
        float4 u1 = *(const float4*)(encrow + 4);
        bf16x8 pk;
        pk[0] = (__bf16)u0.x; pk[1] = (__bf16)u0.y; pk[2] = (__bf16)u0.z; pk[3] = (__bf16)u0.w;
        pk[4] = (__bf16)u1.x; pk[5] = (__bf16)u1.y; pk[6] = (__bf16)u1.z; pk[7] = (__bf16)u1.w;
        Abuf[0][srow][sg] = pk;
    }
    // prologue: B frags for it=0 (f = ks*4 + ni)
    bf16x8 bA[8], bB[8];
    #pragma unroll
    for (int f = 0; f < 8; ++f)
        bA[f] = *(const bf16x8*)(bbase + (size_t)((f & 3) * 16) * EE + (f >> 2) * 32);
    __syncthreads();

    const int NIT = EE / 64;   // 32 (even)
    for (int itp = 0; itp < NIT / 2; ++itp) {
        const int it0 = 2 * itp, it1 = it0 + 1;

        // ================ iteration it0 (A in Abuf[0], B in bA) ================
        #pragma unroll
        for (int f = 0; f < 8; ++f)   // prefetch B for it1
            bB[f] = *(const bf16x8*)(bbase + (size_t)((f & 3) * 16) * EE + it1 * 64 + (f >> 2) * 32);
        float4 p0 = *(const float4*)(encrow + it1 * 64);        // A HBM prefetch for it1
        float4 p1 = *(const float4*)(encrow + it1 * 64 + 4);
        #pragma unroll
        for (int ks = 0; ks < 2; ++ks) {
            bf16x8 afr[4];
            #pragma unroll
            for (int mi = 0; mi < 4; ++mi)
                afr[mi] = Abuf[0][mi * 16 + ar][(ks * 4 + agr) ^ (ar & 7)];
            #pragma unroll
            for (int mi = 0; mi < 4; ++mi)
                #pragma unroll
                for (int ni = 0; ni < 4; ++ni)
                    acc[mi][ni] = __builtin_amdgcn_mfma_f32_16x16x32_bf16(afr[mi], bA[ks * 4 + ni], acc[mi][ni], 0, 0, 0);
        }
        {   // write A tile it1 -> Abuf[1]
            bf16x8 pk;
            pk[0] = (__bf16)p0.x; pk[1] = (__bf16)p0.y; pk[2] = (__bf16)p0.z; pk[3] = (__bf16)p0.w;
            pk[4] = (__bf16)p1.x; pk[5] = (__bf16)p1.y; pk[6] = (__bf16)p1.z; pk[7] = (__bf16)p1.w;
            Abuf[1][srow][sg] = pk;
        }
        __syncthreads();

        // ================ iteration it1 (A in Abuf[1], B in bB) ================
        const bool more = (it1 + 1 < NIT);
        if (more) {
            #pragma unroll
            for (int f = 0; f < 8; ++f)   // prefetch B for it1+1
                bA[f] = *(const bf16x8*)(bbase + (size_t)((f & 3) * 16) * EE + (it1 + 1) * 64 + (f >> 2) * 32);
        }
        float4 q0, q1;
        if (more) {
            q0 = *(const float4*)(encrow + (it1 + 1) * 64);
            q1 = *(const float4*)(encrow + (it1 + 1) * 64 + 4);
        }
        #pragma unroll
        for (int ks = 0; ks < 2; ++ks) {
            bf16x8 afr[4];
            #pragma unroll
            for (int mi = 0; mi < 4; ++mi)
                afr[mi] = Abuf[1][mi * 16 + ar][(ks * 4 + agr) ^ (ar & 7)];
            #pragma unroll
            for (int mi = 0; mi < 4; ++mi)
                #pragma unroll
                for (int ni = 0; ni < 4; ++ni)
                    acc[mi][ni] = __builtin_amdgcn_mfma_f32_16x16x32_bf16(afr[mi], bB[ks * 4 + ni], acc[mi][ni], 0, 0, 0);
        }
        if (more) {
            bf16x8 pk;
            pk[0] = (__bf16)q0.x; pk[1] = (__bf16)q0.y; pk[2] = (__bf16)q0.z; pk[3] = (__bf16)q0.w;
            pk[4] = (__bf16)q1.x; pk[5] = (__bf16)q1.y; pk[6] = (__bf16)q1.z; pk[7] = (__bf16)q1.w;
            Abuf[0][srow][sg] = pk;
            __syncthreads();
        }
    }

    // epilogue: tanh(q + s) * v, reduce over this wave's 64 n-cols
    float sred[4][4];
    #pragma unroll
    for (int mi = 0; mi < 4; ++mi)
        #pragma unroll
        for (int r = 0; r < 4; ++r) sred[mi][r] = 0.f;
    #pragma unroll
    for (int ni = 0; ni < 4; ++ni) {
        const int col = n0w + ni * 16 + ar;
        const float qa = qs[col], va = vs[col];
        #pragma unroll
        for (int mi = 0; mi < 4; ++mi)
            #pragma unroll
            for (int r = 0; r < 4; ++r)
                sred[mi][r] += tanhf(qa + acc[mi][ni][r]) * va;
    }
    #pragma unroll
    for (int mi = 0; mi < 4; ++mi)
        #pragma unroll
        for (int r = 0; r < 4; ++r) {
            #pragma unroll
            for (int off = 1; off < 16; off <<= 1)
                sred[mi][r] += __shfl_xor(sred[mi][r], off, 64);
        }
    if (ar == 0) {
        #pragma unroll
        for (int mi = 0; mi < 4; ++mi)
            #pragma unroll
            for (int r = 0; r < 4; ++r)
                wred[wv][mi * 16 + agr * 4 + r] = sred[mi][r];
    }
    __syncthreads();
    if (tid < 64) {
        float s = bv[0];
        #pragma unroll
        for (int w = 0; w < 8; ++w) s += wred[w][tid];
        float mx = s;
        #pragma unroll
        for (int off = 1; off < 64; off <<= 1) mx = fmaxf(mx, __shfl_xor(mx, off, 64));
        float p = expf(s - mx);
        float sum = p;
        #pragma unroll
        for (int off = 1; off < 64; off <<= 1) sum += __shfl_xor(sum, off, 64);
        attnG[(size_t)b * TT + tid] = p / sum;
    }
}

// ---------------- context = sum_t attn[t] * enc[b,t,:] ----------------
__global__ void k_context(const float* __restrict__ enc, const float* __restrict__ attnG,
                          float* __restrict__ ctx) {
    __shared__ float attn[TT];
    const int b = blockIdx.y;
    const int tid = threadIdx.x;
    if (tid < 64) attn[tid] = attnG[(size_t)b * TT + tid];
    __syncthreads();
    const int e = blockIdx.x * 1024 + tid * 4;
    const float* encb = enc + (size_t)b * TT * EE + e;
    float4 acc = {0.f, 0.f, 0.f, 0.f};
    #pragma unroll 4
    for (int t = 0; t < TT; ++t) {
        float a = attn[t];
        float4 ev = *(const float4*)&encb[(size_t)t * EE];
        acc.x = fmaf(a, ev.x, acc.x);
        acc.y = fmaf(a, ev.y, acc.y);
        acc.z = fmaf(a, ev.z, acc.z);
        acc.w = fmaf(a, ev.w, acc.w);
    }
    *(float4*)&ctx[(size_t)b * EE + e] = acc;
}

// ------- z = [ctx, emb[c], hidden] @ [wx; wh] via bf16 MFMA, K split 4 ways -------
#define ZKS 4
#define ZKC (KLSTM / ZKS)    // 704
#define ZNIT (ZKC / 32)      // 22
__global__ void k_z(const float* __restrict__ ctx, const float* __restrict__ emb,
                    const int* __restrict__ cidx, const float* __restrict__ hidden,
                    const __bf16* __restrict__ wt, float* __restrict__ zp) {
    __shared__ bf16x8 Abuf[32][ZKC / 8];   // [row][granule], granule ^= row&7 (45 KB)
    __shared__ int cbs[32];
    const int tid = threadIdx.x;
    const int l = tid & 63, wv = tid >> 6;
    const int b0  = blockIdx.y * 32;
    const int kc0 = blockIdx.z * ZKC;
    const int nw  = blockIdx.x * 256 + wv * 64;

    if (tid < 32) cbs[tid] = cidx[b0 + tid];
    __syncthreads();

    {
        const int srow = tid >> 3, g0 = tid & 7;
        const int bg = b0 + srow;
        const int erow = cbs[srow];
        #pragma unroll
        for (int i = 0; i < 11; ++i) {
            int g = g0 + 8 * i;
            int k = kc0 + g * 8;
            const float* src;
            if (k < EE)             src = &ctx[(size_t)bg * EE + k];
            else if (k < EE + EMBD) src = &emb[(size_t)erow * EMBD + (k - EE)];
            else                    src = &hidden[(size_t)bg * DD + (k - EE - EMBD)];
            float4 u0 = *(const float4*)src;
            float4 u1 = *(const float4*)(src + 4);
            bf16x8 pk;
            pk[0] = (__bf16)u0.x; pk[1] = (__bf16)u0.y; pk[2] = (__bf16)u0.z; pk[3] = (__bf16)u0.w;
            pk[4] = (__bf16)u1.x; pk[5] = (__bf16)u1.y; pk[6] = (__bf16)u1.z; pk[7] = (__bf16)u1.w;
            Abuf[srow][g ^ (srow & 7)] = pk;
        }
    }
    __syncthreads();

    const int ar = l & 15, agr = l >> 4;
    const __bf16* bbase = wt + (size_t)(nw + ar) * KLSTM + kc0 + agr * 8;

    f32x4 acc[2][4];
    #pragma unroll
    for (int mt = 0; mt < 2; ++mt)
        #pragma unroll
        for (int f = 0; f < 4; ++f)
            acc[mt][f] = (f32x4){0.f, 0.f, 0.f, 0.f};

    bf16x8 bA[4], bBv[4];
    #pragma unroll
    for (int f = 0; f < 4; ++f)
        bA[f] = *(const bf16x8*)(bbase + (size_t)f * 16 * KLSTM);

    for (int itp = 0; itp < ZNIT / 2; ++itp) {
        const int it0 = 2 * itp, it1 = 2 * itp + 1;
        #pragma unroll
        for (int f = 0; f < 4; ++f)
            bBv[f] = *(const bf16x8*)(bbase + (size_t)f * 16 * KLSTM + it1 * 32);
        {
            bf16x8 a0 = Abuf[ar][(it0 * 4 + agr) ^ (ar & 7)];
            bf16x8 a1 = Abuf[16 + ar][(it0 * 4 + agr) ^ (ar & 7)];
            #pragma unroll
            for (int f = 0; f < 4; ++f) {
                acc[0][f] = __builtin_amdgcn_mfma_f32_16x16x32_bf16(a0, bA[f], acc[0][f], 0, 0, 0);
                acc[1][f] = __builtin_amdgcn_mfma_f32_16x16x32_bf16(a1, bA[f], acc[1][f], 0, 0, 0);
            }
        }
        const int it2 = (it1 + 1 < ZNIT) ? it1 + 1 : it1;
        #pragma unroll
        for (int f = 0; f < 4; ++f)
            bA[f] = *(const bf16x8*)(bbase + (size_t)f * 16 * KLSTM + it2 * 32);
        {
            bf16x8 a0 = Abuf[ar][(it1 * 4 + agr) ^ (ar & 7)];
            bf16x8 a1 = Abuf[16 + ar][(it1 * 4 + agr) ^ (ar & 7)];
            #pragma unroll
            for (int f = 0; f < 4; ++f) {
                acc[0][f] = __builtin_amdgcn_mfma_f32_16x16x32_bf16(a0, bBv[f], acc[0][f], 0, 0, 0);
                acc[1][f] = __builtin_amdgcn_mfma_f32_16x16x32_bf16(a1, bBv[f], acc[1][f], 0, 0, 0);
            }
        }
    }

    float* zpo = zp + (size_t)blockIdx.z * BB * N4D;
    #pragma unroll
    for (int mt = 0; mt < 2; ++mt)
        #pragma unroll
        for (int f = 0; f < 4; ++f)
            #pragma unroll
            for (int r = 0; r < 4; ++r)
                zpo[(size_t)(b0 + mt * 16 + agr * 4 + r) * N4D + nw + f * 16 + ar] = acc[mt][f][r];
}

// ---------------- LSTM gates: sum K-split partials + bias, then activations ----------------
__global__ void k_gates(const float* __restrict__ zp, const float* __restrict__ carry,
                        const float* __restrict__ bl,
                        float* __restrict__ hout, float* __restrict__ cout) {
    const int b = blockIdx.x, tid = threadIdx.x;
    const size_t P = (size_t)BB * N4D;
    #pragma unroll
    for (int r = 0; r < 2; ++r) {
        int d = tid + r * 256;
        float zi = bl[d], zf = bl[DD + d], zg = bl[2 * DD + d], zo = bl[3 * DD + d];
        #pragma unroll
        for (int ks = 0; ks < ZKS; ++ks) {
            const float* zb = zp + ks * P + (size_t)b * N4D;
            zi += zb[d];
            zf += zb[DD + d];
            zg += zb[2 * DD + d];
            zo += zb[3 * DD + d];
        }
        float c = carry[(size_t)b * DD + d];
        float cn = sigf(zf) * c + sigf(zi) * tanhf(zg);
        float hn = sigf(zo) * tanhf(cn);
        cout[(size_t)b * DD + d] = cn;
        hout[(size_t)b * DD + d] = hn;
    }
}

// ---------------- logits = h_new @ wp + bp  via bf16 MFMA ----------------
__global__ __launch_bounds__(256, 4) void k_logits(
        const float* __restrict__ hnew, const __bf16* __restrict__ wpt,
        const float* __restrict__ bp, float* __restrict__ logits) {
    __shared__ bf16x8 Abuf[64][8];
    __shared__ bf16x8 Bbuf[128][8];
    __shared__ float bps[128];
    const int tid = threadIdx.x;
    const int nb = blockIdx.x % 80, mb = blockIdx.x / 80;
    const int m0 = mb * 64, n0 = nb * 128;
    const int l = tid & 63, wv = tid >> 6;
    const int wm = wv >> 1, wn = wv & 1;
    const int ar = l & 15, agr = l >> 4;

    if (tid < 128) {
        int j = n0 + tid;
        bps[tid] = (j < VV) ? bp[j] : 0.f;
    }

    const int arow = tid >> 2, ag0 = (tid & 3) * 2;
    const float* aptr = hnew + (size_t)(m0 + arow) * DD + ag0 * 8;
    const int brow = tid >> 1, bg0 = (tid & 1) * 4;
    const __bf16* bptr = wpt + (size_t)(n0 + brow) * DD + bg0 * 8;

    f32x4 acc[2][4];
    #pragma unroll
    for (int mi = 0; mi < 2; ++mi)
        #pragma unroll
        for (int ni = 0; ni < 4; ++ni)
            acc[mi][ni] = (f32x4){0.f, 0.f, 0.f, 0.f};

    float4 af[4];
    bf16x8 bstg[4];
    #pragma unroll
    for (int j = 0; j < 4; ++j) af[j] = *(const float4*)(aptr + j * 4);
    #pragma unroll
    for (int i = 0; i < 4; ++i) bstg[i] = *(const bf16x8*)(bptr + i * 8);

    const int NIT = DD / 64;   // 8
    for (int it = 0; it < NIT; ++it) {
        if (it > 0) __syncthreads();
        {
            bf16x8 pk;
            pk[0] = (__bf16)af[0].x; pk[1] = (__bf16)af[0].y; pk[2] = (__bf16)af[0].z; pk[3] = (__bf16)af[0].w;
            pk[4] = (__bf16)af[1].x; pk[5] = (__bf16)af[1].y; pk[6] = (__bf16)af[1].z; pk[7] = (__bf16)af[1].w;
            Abuf[arow][ag0 ^ (arow & 7)] = pk;
            pk[0] = (__bf16)af[2].x; pk[1] = (__bf16)af[2].y; pk[2] = (__bf16)af[2].z; pk[3] = (__bf16)af[2].w;
            pk[4] = (__bf16)af[3].x; pk[5] = (__bf16)af[3].y; pk[6] = (__bf16)af[3].z; pk[7] = (__bf16)af[3].w;
            Abuf[arow][(ag0 + 1) ^ (arow & 7)] = pk;
        }
        #pragma unroll
        for (int i = 0; i < 4; ++i)
            Bbuf[brow][(bg0 + i) ^ (brow & 7)] = bstg[i];
        if (it + 1 < NIT) {
            const int k1 = (it + 1) * 64;
            #pragma unroll
            for (int j = 0; j < 4; ++j) af[j] = *(const float4*)(aptr + k1 + j * 4);
            #pragma unroll
            for (int i = 0; i < 4; ++i) bstg[i] = *(const bf16x8*)(bptr + k1 + i * 8);
        }
        __syncthreads();
        #pragma unroll
        for (int ks = 0; ks < 2; ++ks) {
            bf16x8 afr[2], bfr[4];
            #pragma unroll
            for (int mi = 0; mi < 2; ++mi)
                afr[mi] = Abuf[wm * 32 + mi * 16 + ar][(ks * 4 + agr) ^ (ar & 7)];
            #pragma unroll
            for (int ni = 0; ni < 4; ++ni)
                bfr[ni] = Bbuf[wn * 64 + ni * 16 + ar][(ks * 4 + agr) ^ (ar & 7)];
            #pragma unroll
            for (int mi = 0; mi < 2; ++mi)
                #pragma unroll
                for (int ni = 0; ni < 4; ++ni)
                    acc[mi][ni] = __builtin_amdgcn_mfma_f32_16x16x32_bf16(afr[mi], bfr[ni], acc[mi][ni], 0, 0, 0);
        }
    }

    #pragma unroll
    for (int mi = 0; mi < 2; ++mi)
        #pragma unroll
        for (int ni = 0; ni < 4; ++ni) {
            const int colL = wn * 64 + ni * 16 + ar;
            const int col = n0 + colL;
            if (col < VV) {
                const float bb = bps[colL];
                #pragma unroll
                for (int r = 0; r < 4; ++r) {
                    const int row = m0 + wm * 32 + mi * 16 + agr * 4 + r;
                    logits[(size_t)row * VV + col] = acc[mi][ni][r] + bb;
                }
            }
        }
}

extern "C" void kernel_launch(void* const* d_in, const int* in_sizes, int n_in,
                              void* d_out, int out_size, void* d_ws, size_t ws_size,
                              hipStream_t stream) {
    const int*   cidx   = (const int*)d_in[0];
    const float* hidden = (const float*)d_in[1];
    const float* carry  = (const float*)d_in[2];
    const float* enc    = (const float*)d_in[3];
    const float* emb    = (const float*)d_in[4];
    const float* w1     = (const float*)d_in[5];
    const float* b1     = (const float*)d_in[6];
    const float* w2     = (const float*)d_in[7];
    const float* b2     = (const float*)d_in[8];
    const float* vvec   = (const float*)d_in[9];
    const float* bv     = (const float*)d_in[10];
    const float* wx     = (const float*)d_in[11];
    const float* wh     = (const float*)d_in[12];
    const float* bl     = (const float*)d_in[13];
    const float* wp     = (const float*)d_in[14];
    const float* bp     = (const float*)d_in[15];

    float* out    = (float*)d_out;
    float* logits = out;
    float* hout   = out + (size_t)BB * VV;
    float* cout   = hout + (size_t)BB * DD;

    float* ws    = (float*)d_ws;
    float* qq    = ws;                          // B*A     = 131072 f32
    float* attnG = qq + (size_t)BB * AA;        // B*T     = 16384 f32
    float* ctx   = attnG + (size_t)BB * TT;     // B*E     = 524288 f32
    float* zp    = ctx + (size_t)BB * EE;       // ZKS*B*4D = 2097152 f32
    __bf16* wxh_t = (__bf16*)(zp + (size_t)ZKS * BB * N4D);   // 2048*2816 bf16 = 11.5 MB
    __bf16* wpt  = (__bf16*)(wxh_t + (size_t)N4D * KLSTM);    // 10240*512 bf16 = 10.5 MB
    // w2t (512x2048 bf16 = 2 MB) aliases ctx: consumed by k_attn BEFORE k_context writes ctx
    __bf16* w2t  = (__bf16*)ctx;

    hipLaunchKernelGGL(k_w2t,     dim3(EE / 32, AA / 32),    dim3(32, 8), 0, stream, w2, w2t);
    hipLaunchKernelGGL(k_wxht,    dim3(KLSTM / 32, N4D / 32), dim3(32, 8), 0, stream, wx, wh, wxh_t);
    hipLaunchKernelGGL(k_wpt,     dim3(DD / 32, VPAD / 32),  dim3(32, 8), 0, stream, wp, wpt);
    hipLaunchKernelGGL(k_q,       dim3(BB),                  dim3(256), 0, stream, hidden, w1, b1, b2, qq);
    hipLaunchKernelGGL(k_attn,    dim3(BB),                  dim3(512), 0, stream, enc, w2t, qq, vvec, bv, attnG);
    hipLaunchKernelGGL(k_context, dim3(2, BB),               dim3(256), 0, stream, enc, attnG, ctx);
    hipLaunchKernelGGL(k_z,       dim3(N4D / 256, BB / 32, ZKS), dim3(256), 0, stream, ctx, emb, cidx, hidden, wxh_t, zp);
    hipLaunchKernelGGL(k_gates,   dim3(BB),                  dim3(256), 0, stream, zp, carry, bl, hout, cout);
    hipLaunchKernelGGL(k_logits,  dim3(320),                 dim3(256), 0, stream, hout, wpt, bp, logits);
}